// Round 7
// baseline (569.172 us; speedup 1.0000x reference)
//
#include <hip/hip_runtime.h>
#include <hip/hip_bf16.h>

#define CDIM 256
#define EPS 1e-5f
#define SLOPE 0.01f

using f32x4  = __attribute__((ext_vector_type(4))) float;
typedef __bf16 bf16x8 __attribute__((ext_vector_type(8)));
typedef unsigned short u16x8 __attribute__((ext_vector_type(8)));

// ---------------- workspace layout ----------------
enum : size_t {
  OFF_WS_HF   = 0,
  OFF_WS_LF   = 9216,
  OFF_WP_HF   = 20480,
  OFF_BS_HF   = 21504,
  OFF_WP_LF   = 22528,
  OFF_BS_LF   = 23552,
  OFF_MEAN_HF = 24576,
  OFF_RSTD_HF = 25600,
  OFF_MEAN_LF = 26624,
  OFF_RSTD_LF = 27648,
  OFF_U16     = 32768,          // start of ushort region (float units)
};
// ushort offsets relative to u16 base
enum : size_t {
  U_YH  = 0,          // [4][128][128][256] bf16
  U_YL  = 16777216,   // [4][64][64][256]
  U_HFA = 20971520,   // [4][128][128][256]
  U_LFA = 37748736,   // [4][64][64][256]
  U_HFP = 41943040,   // [4][64][64][256]
  U_PK  = 46137344,   // 6 packed weights, each 589824
  PK_SZ = 589824,
  U_END = U_PK + 6 * PK_SZ,
};
enum : size_t { TOTAL_F = OFF_U16 + (U_END + 1) / 2 };

__device__ float g_scratch[TOTAL_F];

__device__ __forceinline__ int refl(int q, int n) {
  return q < 0 ? -q : (q >= n ? 2 * n - 2 - q : q);
}
__device__ __forceinline__ float lrelu(float v) { return v >= 0.f ? v : SLOPE * v; }
__device__ __forceinline__ unsigned short f2bf(float f) {
  unsigned int u = __float_as_uint(f);
  u += 0x7fffu + ((u >> 16) & 1u);
  return (unsigned short)(u >> 16);
}
__device__ __forceinline__ float bf2f(unsigned short h) {
  return __uint_as_float(((unsigned int)h) << 16);
}
__device__ __forceinline__ void gload_lds16(const void* g, void* l) {
  __builtin_amdgcn_global_load_lds(
      (const __attribute__((address_space(1))) unsigned int*)g,
      (__attribute__((address_space(3))) unsigned int*)l, 16, 0, 0);
}

// ---------------- kernel_predict: spatial weights ----------------
__global__ __launch_bounds__(256) void k_ws(const float* __restrict__ s,
                                            const float* __restrict__ sw,
                                            const float* __restrict__ sb,
                                            float* __restrict__ ws_out) {
  int bo = blockIdx.x;
  int o = bo & (CDIM - 1);
  int c = threadIdx.x;
  int b = bo >> 8;
  float sv[9], wv[9];
  const float* sp = s + (size_t)(b * CDIM + c) * 9;
  const float* wp = sw + (size_t)(o * CDIM + c) * 9;
#pragma unroll
  for (int i = 0; i < 9; i++) { sv[i] = sp[i]; wv[i] = wp[i]; }
  float out9[9];
#pragma unroll
  for (int i = 0; i < 3; i++)
#pragma unroll
    for (int j = 0; j < 3; j++) {
      float a = 0.f;
#pragma unroll
      for (int dy = 0; dy < 3; dy++) {
        int u = i + dy - 1; u = (u < 0) ? 1 : (u > 2 ? 1 : u);
#pragma unroll
        for (int dx = 0; dx < 3; dx++) {
          int v = j + dx - 1; v = (v < 0) ? 1 : (v > 2 ? 1 : v);
          a += sv[u * 3 + v] * wv[dy * 3 + dx];
        }
      }
      out9[i * 3 + j] = a;
    }
  __shared__ float red[256 * 9];
#pragma unroll
  for (int i = 0; i < 9; i++) red[c * 9 + i] = out9[i];
  __syncthreads();
  for (int st = 128; st > 0; st >>= 1) {
    if (c < st)
#pragma unroll
      for (int i = 0; i < 9; i++) red[c * 9 + i] += red[(c + st) * 9 + i];
    __syncthreads();
  }
  if (c < 9) ws_out[(size_t)bo * 9 + c] = red[c] + sb[o];
}

// ---------------- pooled + w_point / bias (fused) ----------------
__global__ __launch_bounds__(256) void k_point(const float* __restrict__ s,
                                               const float* __restrict__ pw,
                                               const float* __restrict__ pb,
                                               const float* __restrict__ bw,
                                               const float* __restrict__ bb,
                                               float* __restrict__ wp_out,
                                               float* __restrict__ bs_out) {
  int b = blockIdx.x, o = threadIdx.x;
  __shared__ float pl[CDIM];
  const float* sp = s + (size_t)(b * CDIM + o) * 9;
  float a9 = 0.f;
#pragma unroll
  for (int j = 0; j < 9; j++) a9 += sp[j];
  pl[o] = a9 * (1.f / 9.f);
  __syncthreads();
  float a = pb[o], d = bb[o];
  for (int c = 0; c < CDIM; c++) {
    float p = pl[c];
    a += p * pw[o * CDIM + c];
    d += p * bw[o * CDIM + c];
  }
  wp_out[b * CDIM + o] = a;
  bs_out[b * CDIM + o] = d;
}

__global__ __launch_bounds__(256) void k_istats(const float* __restrict__ x,
                                                float* __restrict__ mean,
                                                float* __restrict__ rstd, int HW) {
  int plane = blockIdx.x;
  const float4* p = (const float4*)(x + (size_t)plane * HW);
  int n4 = HW >> 2;
  float s = 0.f, q = 0.f;
  for (int i = threadIdx.x; i < n4; i += 256) {
    float4 v = p[i];
    s += v.x + v.y + v.z + v.w;
    q += v.x * v.x + v.y * v.y + v.z * v.z + v.w * v.w;
  }
  __shared__ float rs[256], rq[256];
  rs[threadIdx.x] = s; rq[threadIdx.x] = q;
  __syncthreads();
  for (int st = 128; st > 0; st >>= 1) {
    if (threadIdx.x < st) {
      rs[threadIdx.x] += rs[threadIdx.x + st];
      rq[threadIdx.x] += rq[threadIdx.x + st];
    }
    __syncthreads();
  }
  if (threadIdx.x == 0) {
    float m = rs[0] / HW;
    float v = rq[0] / HW - m * m;
    mean[plane] = m;
    rstd[plane] = rsqrtf(v + EPS);
  }
}

// ---------------- weight pack: OIHW f32 -> [tap][icc][mf][lane][8] bf16 (6 mats) ----------------
__global__ void k_packw6(const float* __restrict__ w0, const float* __restrict__ w1,
                         const float* __restrict__ w2, const float* __restrict__ w3,
                         const float* __restrict__ w4, const float* __restrict__ w5,
                         unsigned short* __restrict__ pk) {
  const float* ws[6] = {w0, w1, w2, w3, w4, w5};
  int seg = blockIdx.y;
  const float* w = ws[seg];
  int i = blockIdx.x * 256 + threadIdx.x;   // < 589824
  int j = i & 7, l = (i >> 3) & 63, mf = (i >> 9) & 15, icc = (i >> 13) & 7, tap = i >> 16;
  int oc = mf * 16 + (l & 15);
  int ic = icc * 32 + (l >> 4) * 8 + j;
  pk[(size_t)seg * PK_SZ + i] = f2bf(w[((size_t)oc * 256 + ic) * 9 + tap]);
}

// ---------------- fused IN + dynamic depthwise + pointwise -> NHWC bf16 ----------------
template <int LW>
__global__ __launch_bounds__(256) void k_dwt(const float* __restrict__ x,
                                             const float* __restrict__ ws,
                                             const float* __restrict__ mean,
                                             const float* __restrict__ rstd,
                                             const float* __restrict__ wp,
                                             const float* __restrict__ bs,
                                             unsigned short* __restrict__ out) {
  constexpr int W = 1 << LW, H = W, HW = W * W;
  int t = threadIdx.x;
  int xt = (LW > 6) ? (blockIdx.x & ((W >> 6) - 1)) : 0;
  int icb = (LW > 6) ? (blockIdx.x >> (LW - 6)) : blockIdx.x;
  int y = blockIdx.y, b = blockIdx.z;
  __shared__ unsigned short tr[64][66];
  int xl = t & 63;
  int xx = xt * 64 + xl;
  int sy0 = refl(y - 1, H), sy1 = y, sy2 = refl(y + 1, H);
  int sx0 = refl(xx - 1, W), sx2 = refl(xx + 1, W);
#pragma unroll
  for (int rr = 0; rr < 16; ++rr) {
    int icl = rr * 4 + (t >> 6);
    int plane = b * CDIM + icb * 64 + icl;
    const float* xp = x + (size_t)plane * HW;
    float m = mean[plane], r = rstd[plane], sc = wp[plane], bi = bs[plane];
    const float* w9 = ws + (size_t)plane * 9;
    float a = w9[0] * (xp[sy0 * W + sx0] - m) + w9[1] * (xp[sy0 * W + xx] - m) +
              w9[2] * (xp[sy0 * W + sx2] - m) + w9[3] * (xp[sy1 * W + sx0] - m) +
              w9[4] * (xp[sy1 * W + xx] - m) + w9[5] * (xp[sy1 * W + sx2] - m) +
              w9[6] * (xp[sy2 * W + sx0] - m) + w9[7] * (xp[sy2 * W + xx] - m) +
              w9[8] * (xp[sy2 * W + sx2] - m);
    tr[icl][xl] = f2bf(a * r * sc + bi);
  }
  __syncthreads();
  // vectorized NHWC store: 64 px x 64 ch, u16x8 per store
#pragma unroll
  for (int it2 = 0; it2 < 2; ++it2) {
    int s2 = it2 * 256 + t;          // 0..511
    int xl2 = s2 >> 3;               // 0..63
    int cg = s2 & 7;                 // 0..7
    u16x8 v;
#pragma unroll
    for (int j = 0; j < 8; j++) v[j] = tr[cg * 8 + j][xl2];
    *(u16x8*)&out[((size_t)((b * H + y) * W + xt * 64 + xl2)) * CDIM + icb * 64 + cg * 8] = v;
  }
}

// ---------------- 2x2 avg pool on NHWC bf16 (vectorized: 8 ch / thread) ----------------
__global__ __launch_bounds__(256) void k_pool_nhwc(const unsigned short* __restrict__ in,
                                                   unsigned short* __restrict__ out) {
  int i = blockIdx.x * 256 + threadIdx.x;   // < 4*64*64*32
  int cg = i & 31;
  int p = i >> 5;                            // (b*64+Y)*64+X
  int X = p & 63, Y = (p >> 6) & 63, b = p >> 12;
  const unsigned short* s =
      in + ((size_t)(b * 128 + 2 * Y) * 128 + 2 * X) * CDIM + cg * 8;
  u16x8 v0 = *(const u16x8*)(s);
  u16x8 v1 = *(const u16x8*)(s + CDIM);
  u16x8 v2 = *(const u16x8*)(s + 128 * CDIM);
  u16x8 v3 = *(const u16x8*)(s + 128 * CDIM + CDIM);
  u16x8 r;
#pragma unroll
  for (int j = 0; j < 8; j++)
    r[j] = f2bf(0.25f * (bf2f(v0[j]) + bf2f(v1[j]) + bf2f(v2[j]) + bf2f(v3[j])));
  *(u16x8*)(out + (size_t)p * CDIM + cg * 8) = r;
}

// ---------------- MFMA implicit-GEMM 3x3 reflect conv ----------------
// block 256 (4 waves), tile 64 oc x 256 pixels (R5 structure). Input tile in
// LDS (36.9 KB only); WEIGHTS go global->VGPR directly (L2/L3-hot packed
// fragments, coalesced 1KB wave loads, one tap prefetched ahead) -- halves
// per-wave LDS read traffic -> MFMA-bound. 3 blocks/CU anti-phased.
// 1D grid, XCD-chunked bijective swizzle. setprio around MFMA cluster.
template <int LW, bool DUAL, bool UPSB, bool NCHWOUT>
__global__ __launch_bounds__(256, 3) void k_conv_mfma(
    const unsigned short* __restrict__ srcA, const unsigned short* __restrict__ srcB,
    const unsigned short* __restrict__ wpkA, const unsigned short* __restrict__ wpkB,
    const float* __restrict__ bias, void* __restrict__ outp) {
  constexpr int W = 1 << LW, H = W, HW = W * W;
  constexpr int ROWS = 256 >> LW;       // pixel rows per block
  constexpr int R = ROWS + 2, Cw = W + 2;
  constexpr int RC = R * Cw;
  constexpr int RCPAD = (RC + 63) & ~63;
  constexpr int NIT = RCPAD / 64;
  __shared__ __align__(16) unsigned short tin[RCPAD * 32];        // input tile, 32 ic

  const int t = threadIdx.x;
  const int l = t & 63, wv = t >> 6;
  const int l15 = l & 15, l4 = l >> 4;

  // XCD-chunked bijective swizzle (nwg divisible by 8)
  const int hwid = blockIdx.x;
  const int nwg = gridDim.x;
  const int wk = (hwid & 7) * (nwg >> 3) + (hwid >> 3);
  const int mb = wk & 3;
  const int pixbase = (wk >> 2) * 256;
  const int b = pixbase >> (2 * LW);
  const int y0 = (pixbase >> LW) & (H - 1);

  f32x4 acc[4][4];
#pragma unroll
  for (int mi = 0; mi < 4; mi++)
#pragma unroll
    for (int nf = 0; nf < 4; nf++) acc[mi][nf] = (f32x4){0.f, 0.f, 0.f, 0.f};

  const int nsrc = DUAL ? 2 : 1;
  for (int src = 0; src < nsrc; ++src) {
    const unsigned short* ysrc = src ? srcB : srcA;
    const unsigned short* wpk = src ? wpkB : wpkA;
    const bool ups = UPSB && (src == 1);

    // hoist staging addresses out of the K loop
    const unsigned short* inptr[NIT];
#pragma unroll
    for (int it = 0; it < NIT; ++it) {
      int rc = it * 64 + (t >> 2);
      int rcc = rc < RC - 1 ? rc : RC - 1;
      int r = rcc / Cw, tc = rcc - r * Cw;
      int gy = refl(y0 - 1 + r, H);
      int gx = refl(tc - 1, W);
      int sy, sx, sw;
      if (ups) { sy = gy >> 1; sx = gx >> 1; sw = W >> 1; }
      else     { sy = gy;      sx = gx;      sw = W; }
      int gsrc = (t & 3) ^ (tc & 3);   // ic-slot XOR swizzle (source side)
      inptr[it] = ysrc + (((size_t)(b * sw + sy) * sw + sx) * CDIM + gsrc * 8);
    }
    // per-lane weight fragment base: frag(tap,icc,mi) at wb + ((tap*8+icc)*16+mi)*512
    const unsigned short* wb = wpk + ((size_t)(mb * 4) * 64 + l) * 8;

    for (int icc = 0; icc < 8; ++icc) {
      __syncthreads();
#pragma unroll
      for (int it = 0; it < NIT; ++it)
        gload_lds16(inptr[it] + icc * 32, &tin[(size_t)(it * 256 + t) * 8]);

      // prefetch tap-0 weights (global -> regs, coalesced 1KB per wave per frag)
      bf16x8 af2[2][4];
#pragma unroll
      for (int mi = 0; mi < 4; mi++)
        af2[0][mi] = *(const bf16x8*)(wb + ((size_t)((0 * 8 + icc) * 16 + mi)) * 512);
      __syncthreads();

      __builtin_amdgcn_s_setprio(1);
#pragma unroll
      for (int tap = 0; tap < 9; ++tap) {
        const int dy = tap / 3, dx = tap - 3 * (tap / 3);
        if (tap < 8) {
#pragma unroll
          for (int mi = 0; mi < 4; mi++)
            af2[(tap + 1) & 1][mi] =
                *(const bf16x8*)(wb + ((size_t)(((tap + 1) * 8 + icc) * 16 + mi)) * 512);
        }
#pragma unroll
        for (int nf = 0; nf < 4; nf++) {
          int pl = wv * 64 + nf * 16 + l15;
          int py = pl >> LW;
          int c = pl & (W - 1);
          int tcol = c + dx;
          int idx16 = ((py + dy) * Cw + tcol) * 4 + (l4 ^ (tcol & 3));
          bf16x8 bfv = *(const bf16x8*)&tin[(size_t)idx16 * 8];
#pragma unroll
          for (int mi = 0; mi < 4; mi++)
            acc[mi][nf] = __builtin_amdgcn_mfma_f32_16x16x32_bf16(af2[tap & 1][mi], bfv,
                                                                  acc[mi][nf], 0, 0, 0);
        }
      }
      __builtin_amdgcn_s_setprio(0);
    }
  }

  // epilogue
#pragma unroll
  for (int mi = 0; mi < 4; mi++) {
    int oc0 = mb * 64 + mi * 16 + l4 * 4;
    float bv[4];
#pragma unroll
    for (int rr = 0; rr < 4; rr++) bv[rr] = bias ? bias[oc0 + rr] : 0.f;
#pragma unroll
    for (int nf = 0; nf < 4; nf++) {
      int p = pixbase + wv * 64 + nf * 16 + l15;
      if (NCHWOUT) {
        float* o = (float*)outp;
        int pin = p & (HW - 1);
        int bb2 = p >> (2 * LW);
#pragma unroll
        for (int rr = 0; rr < 4; rr++)
          o[((size_t)(bb2 * CDIM + oc0 + rr)) * HW + pin] = lrelu(acc[mi][nf][rr] + bv[rr]);
      } else {
        unsigned short* o = (unsigned short*)outp;
        ushort4 pk;
        pk.x = f2bf(lrelu(acc[mi][nf][0] + bv[0]));
        pk.y = f2bf(lrelu(acc[mi][nf][1] + bv[1]));
        pk.z = f2bf(lrelu(acc[mi][nf][2] + bv[2]));
        pk.w = f2bf(lrelu(acc[mi][nf][3] + bv[3]));
        *(ushort4*)&o[(size_t)p * CDIM + oc0] = pk;
      }
    }
  }
}

// ---------------- host ----------------
extern "C" void kernel_launch(void* const* d_in, const int* in_sizes, int n_in,
                              void* d_out, int out_size, void* d_ws, size_t ws_size,
                              hipStream_t stream) {
  (void)in_sizes; (void)n_in; (void)out_size;
  const float* c_hf = (const float*)d_in[0];
  const float* c_lf = (const float*)d_in[1];
  const float* s_hf = (const float*)d_in[2];
  const float* s_lf = (const float*)d_in[3];
  const float* h_sw = (const float*)d_in[4];
  const float* h_sb = (const float*)d_in[5];
  const float* h_pw = (const float*)d_in[6];
  const float* h_pb = (const float*)d_in[7];
  const float* h_bw = (const float*)d_in[8];
  const float* h_bb = (const float*)d_in[9];
  const float* l_sw = (const float*)d_in[10];
  const float* l_sb = (const float*)d_in[11];
  const float* l_pw = (const float*)d_in[12];
  const float* l_pb = (const float*)d_in[13];
  const float* l_bw = (const float*)d_in[14];
  const float* l_bb = (const float*)d_in[15];
  const float* ada_h_w = (const float*)d_in[16];
  const float* ada_h_b = (const float*)d_in[17];
  const float* ada_l_w = (const float*)d_in[18];
  const float* ada_l_b = (const float*)d_in[19];
  const float* h2h = (const float*)d_in[20];
  const float* l2h = (const float*)d_in[21];
  const float* h2l = (const float*)d_in[22];
  const float* l2l = (const float*)d_in[23];

  const int B = 4, H = 128, W = 128;

  float* base;
  size_t need = (size_t)TOTAL_F * sizeof(float);
  if (ws_size >= need) {
    base = (float*)d_ws;
  } else {
    void* p = nullptr;
    hipGetSymbolAddress(&p, HIP_SYMBOL(g_scratch));
    base = (float*)p;
  }

  float* ws_hf = base + OFF_WS_HF;
  float* ws_lf = base + OFF_WS_LF;
  float* wp_hf = base + OFF_WP_HF;
  float* bs_hf = base + OFF_BS_HF;
  float* wp_lf = base + OFF_WP_LF;
  float* bs_lf = base + OFF_BS_LF;
  float* mean_hf = base + OFF_MEAN_HF;
  float* rstd_hf = base + OFF_RSTD_HF;
  float* mean_lf = base + OFF_MEAN_LF;
  float* rstd_lf = base + OFF_RSTD_LF;
  unsigned short* u16 = (unsigned short*)(base + OFF_U16);
  unsigned short* yh = u16 + U_YH;
  unsigned short* yl = u16 + U_YL;
  unsigned short* hfA = u16 + U_HFA;
  unsigned short* lfA = u16 + U_LFA;
  unsigned short* hfP = u16 + U_HFP;
  unsigned short* pk      = u16 + U_PK;
  unsigned short* pk_adah = pk + 0 * PK_SZ;
  unsigned short* pk_h2h  = pk + 1 * PK_SZ;
  unsigned short* pk_l2h  = pk + 2 * PK_SZ;
  unsigned short* pk_adal = pk + 3 * PK_SZ;
  unsigned short* pk_l2l  = pk + 4 * PK_SZ;
  unsigned short* pk_h2l  = pk + 5 * PK_SZ;

  float* out_hf = (float*)d_out;
  float* out_lf = (float*)d_out + 16777216;

  // weight packing (6 matrices in one launch)
  k_packw6<<<dim3(2304, 6), dim3(256), 0, stream>>>(ada_h_w, h2h, l2h, ada_l_w, l2l, h2l, pk);

  // kernel_predict
  k_ws<<<dim3(B * CDIM), dim3(256), 0, stream>>>(s_hf, h_sw, h_sb, ws_hf);
  k_ws<<<dim3(B * CDIM), dim3(256), 0, stream>>>(s_lf, l_sw, l_sb, ws_lf);
  k_point<<<dim3(B), dim3(256), 0, stream>>>(s_hf, h_pw, h_pb, h_bw, h_bb, wp_hf, bs_hf);
  k_point<<<dim3(B), dim3(256), 0, stream>>>(s_lf, l_pw, l_pb, l_bw, l_bb, wp_lf, bs_lf);

  // instance norm stats
  k_istats<<<dim3(B * CDIM), dim3(256), 0, stream>>>(c_hf, mean_hf, rstd_hf, H * W);
  k_istats<<<dim3(B * CDIM), dim3(256), 0, stream>>>(c_lf, mean_lf, rstd_lf, (H / 2) * (W / 2));

  // fused IN + depthwise + pointwise -> NHWC bf16
  k_dwt<7><<<dim3(8, 128, 4), dim3(256), 0, stream>>>(c_hf, ws_hf, mean_hf, rstd_hf, wp_hf, bs_hf, yh);
  k_dwt<6><<<dim3(4, 64, 4), dim3(256), 0, stream>>>(c_lf, ws_lf, mean_lf, rstd_lf, wp_lf, bs_lf, yl);

  // ada convs (MFMA), bf16 NHWC out, lrelu
  k_conv_mfma<7, false, false, false><<<dim3(1024), dim3(256), 0, stream>>>(
      yh, nullptr, pk_adah, nullptr, ada_h_b, hfA);
  k_conv_mfma<6, false, false, false><<<dim3(256), dim3(256), 0, stream>>>(
      yl, nullptr, pk_adal, nullptr, ada_l_b, lfA);

  // avgpool hf (vectorized)
  k_pool_nhwc<<<dim3(2048), dim3(256), 0, stream>>>(hfA, hfP);

  // fused output convs (MFMA), f32 NCHW out, lrelu
  k_conv_mfma<7, true, true, true><<<dim3(1024), dim3(256), 0, stream>>>(
      hfA, lfA, pk_h2h, pk_l2h, nullptr, out_hf);
  k_conv_mfma<6, true, false, true><<<dim3(256), dim3(256), 0, stream>>>(
      lfA, hfP, pk_l2l, pk_h2l, nullptr, out_lf);
}

// Round 8
// 495.457 us; speedup vs baseline: 1.1488x; 1.1488x over previous
//
#include <hip/hip_runtime.h>
#include <hip/hip_bf16.h>

#define CDIM 256
#define EPS 1e-5f
#define SLOPE 0.01f

using f32x4  = __attribute__((ext_vector_type(4))) float;
typedef __bf16 bf16x8 __attribute__((ext_vector_type(8)));
typedef unsigned short u16x8 __attribute__((ext_vector_type(8)));

// ---------------- workspace layout ----------------
enum : size_t {
  OFF_WS_HF   = 0,
  OFF_WS_LF   = 9216,
  OFF_WP_HF   = 20480,
  OFF_BS_HF   = 21504,
  OFF_WP_LF   = 22528,
  OFF_BS_LF   = 23552,
  OFF_MEAN_HF = 24576,
  OFF_RSTD_HF = 25600,
  OFF_MEAN_LF = 26624,
  OFF_RSTD_LF = 27648,
  OFF_U16     = 32768,          // start of ushort region (float units)
};
// ushort offsets relative to u16 base
enum : size_t {
  U_YH  = 0,          // [4][128][128][256] bf16
  U_YL  = 16777216,   // [4][64][64][256]
  U_HFA = 20971520,   // [4][128][128][256]
  U_LFA = 37748736,   // [4][64][64][256]
  U_HFP = 41943040,   // [4][64][64][256]
  U_PK  = 46137344,   // 6 packed weights, each 589824
  PK_SZ = 589824,
  U_END = U_PK + 6 * PK_SZ,
};
enum : size_t { TOTAL_F = OFF_U16 + (U_END + 1) / 2 };

__device__ float g_scratch[TOTAL_F];

__device__ __forceinline__ int refl(int q, int n) {
  return q < 0 ? -q : (q >= n ? 2 * n - 2 - q : q);
}
__device__ __forceinline__ float lrelu(float v) { return v >= 0.f ? v : SLOPE * v; }
__device__ __forceinline__ unsigned short f2bf(float f) {
  unsigned int u = __float_as_uint(f);
  u += 0x7fffu + ((u >> 16) & 1u);
  return (unsigned short)(u >> 16);
}
__device__ __forceinline__ float bf2f(unsigned short h) {
  return __uint_as_float(((unsigned int)h) << 16);
}
__device__ __forceinline__ void gload_lds16(const void* g, void* l) {
  __builtin_amdgcn_global_load_lds(
      (const __attribute__((address_space(1))) unsigned int*)g,
      (__attribute__((address_space(3))) unsigned int*)l, 16, 0, 0);
}

// ---------------- kernel_predict: spatial weights ----------------
__global__ __launch_bounds__(256) void k_ws(const float* __restrict__ s,
                                            const float* __restrict__ sw,
                                            const float* __restrict__ sb,
                                            float* __restrict__ ws_out) {
  int bo = blockIdx.x;
  int o = bo & (CDIM - 1);
  int c = threadIdx.x;
  int b = bo >> 8;
  float sv[9], wv[9];
  const float* sp = s + (size_t)(b * CDIM + c) * 9;
  const float* wp = sw + (size_t)(o * CDIM + c) * 9;
#pragma unroll
  for (int i = 0; i < 9; i++) { sv[i] = sp[i]; wv[i] = wp[i]; }
  float out9[9];
#pragma unroll
  for (int i = 0; i < 3; i++)
#pragma unroll
    for (int j = 0; j < 3; j++) {
      float a = 0.f;
#pragma unroll
      for (int dy = 0; dy < 3; dy++) {
        int u = i + dy - 1; u = (u < 0) ? 1 : (u > 2 ? 1 : u);
#pragma unroll
        for (int dx = 0; dx < 3; dx++) {
          int v = j + dx - 1; v = (v < 0) ? 1 : (v > 2 ? 1 : v);
          a += sv[u * 3 + v] * wv[dy * 3 + dx];
        }
      }
      out9[i * 3 + j] = a;
    }
  __shared__ float red[256 * 9];
#pragma unroll
  for (int i = 0; i < 9; i++) red[c * 9 + i] = out9[i];
  __syncthreads();
  for (int st = 128; st > 0; st >>= 1) {
    if (c < st)
#pragma unroll
      for (int i = 0; i < 9; i++) red[c * 9 + i] += red[(c + st) * 9 + i];
    __syncthreads();
  }
  if (c < 9) ws_out[(size_t)bo * 9 + c] = red[c] + sb[o];
}

// ---------------- pooled + w_point / bias (fused) ----------------
__global__ __launch_bounds__(256) void k_point(const float* __restrict__ s,
                                               const float* __restrict__ pw,
                                               const float* __restrict__ pb,
                                               const float* __restrict__ bw,
                                               const float* __restrict__ bb,
                                               float* __restrict__ wp_out,
                                               float* __restrict__ bs_out) {
  int b = blockIdx.x, o = threadIdx.x;
  __shared__ float pl[CDIM];
  const float* sp = s + (size_t)(b * CDIM + o) * 9;
  float a9 = 0.f;
#pragma unroll
  for (int j = 0; j < 9; j++) a9 += sp[j];
  pl[o] = a9 * (1.f / 9.f);
  __syncthreads();
  float a = pb[o], d = bb[o];
  for (int c = 0; c < CDIM; c++) {
    float p = pl[c];
    a += p * pw[o * CDIM + c];
    d += p * bw[o * CDIM + c];
  }
  wp_out[b * CDIM + o] = a;
  bs_out[b * CDIM + o] = d;
}

__global__ __launch_bounds__(256) void k_istats(const float* __restrict__ x,
                                                float* __restrict__ mean,
                                                float* __restrict__ rstd, int HW) {
  int plane = blockIdx.x;
  const float4* p = (const float4*)(x + (size_t)plane * HW);
  int n4 = HW >> 2;
  float s = 0.f, q = 0.f;
  for (int i = threadIdx.x; i < n4; i += 256) {
    float4 v = p[i];
    s += v.x + v.y + v.z + v.w;
    q += v.x * v.x + v.y * v.y + v.z * v.z + v.w * v.w;
  }
  __shared__ float rs[256], rq[256];
  rs[threadIdx.x] = s; rq[threadIdx.x] = q;
  __syncthreads();
  for (int st = 128; st > 0; st >>= 1) {
    if (threadIdx.x < st) {
      rs[threadIdx.x] += rs[threadIdx.x + st];
      rq[threadIdx.x] += rq[threadIdx.x + st];
    }
    __syncthreads();
  }
  if (threadIdx.x == 0) {
    float m = rs[0] / HW;
    float v = rq[0] / HW - m * m;
    mean[plane] = m;
    rstd[plane] = rsqrtf(v + EPS);
  }
}

// ---------------- weight pack: OIHW f32 -> [tap][icc][mf][lane][8] bf16 (6 mats) ----------------
__global__ void k_packw6(const float* __restrict__ w0, const float* __restrict__ w1,
                         const float* __restrict__ w2, const float* __restrict__ w3,
                         const float* __restrict__ w4, const float* __restrict__ w5,
                         unsigned short* __restrict__ pk) {
  const float* ws[6] = {w0, w1, w2, w3, w4, w5};
  int seg = blockIdx.y;
  const float* w = ws[seg];
  int i = blockIdx.x * 256 + threadIdx.x;   // < 589824
  int j = i & 7, l = (i >> 3) & 63, mf = (i >> 9) & 15, icc = (i >> 13) & 7, tap = i >> 16;
  int oc = mf * 16 + (l & 15);
  int ic = icc * 32 + (l >> 4) * 8 + j;
  pk[(size_t)seg * PK_SZ + i] = f2bf(w[((size_t)oc * 256 + ic) * 9 + tap]);
}

// ---------------- fused IN + dynamic depthwise + pointwise -> NHWC bf16 ----------------
template <int LW>
__global__ __launch_bounds__(256) void k_dwt(const float* __restrict__ x,
                                             const float* __restrict__ ws,
                                             const float* __restrict__ mean,
                                             const float* __restrict__ rstd,
                                             const float* __restrict__ wp,
                                             const float* __restrict__ bs,
                                             unsigned short* __restrict__ out) {
  constexpr int W = 1 << LW, H = W, HW = W * W;
  int t = threadIdx.x;
  int xt = (LW > 6) ? (blockIdx.x & ((W >> 6) - 1)) : 0;
  int icb = (LW > 6) ? (blockIdx.x >> (LW - 6)) : blockIdx.x;
  int y = blockIdx.y, b = blockIdx.z;
  __shared__ unsigned short tr[64][66];
  int xl = t & 63;
  int xx = xt * 64 + xl;
  int sy0 = refl(y - 1, H), sy1 = y, sy2 = refl(y + 1, H);
  int sx0 = refl(xx - 1, W), sx2 = refl(xx + 1, W);
#pragma unroll
  for (int rr = 0; rr < 16; ++rr) {
    int icl = rr * 4 + (t >> 6);
    int plane = b * CDIM + icb * 64 + icl;
    const float* xp = x + (size_t)plane * HW;
    float m = mean[plane], r = rstd[plane], sc = wp[plane], bi = bs[plane];
    const float* w9 = ws + (size_t)plane * 9;
    float a = w9[0] * (xp[sy0 * W + sx0] - m) + w9[1] * (xp[sy0 * W + xx] - m) +
              w9[2] * (xp[sy0 * W + sx2] - m) + w9[3] * (xp[sy1 * W + sx0] - m) +
              w9[4] * (xp[sy1 * W + xx] - m) + w9[5] * (xp[sy1 * W + sx2] - m) +
              w9[6] * (xp[sy2 * W + sx0] - m) + w9[7] * (xp[sy2 * W + xx] - m) +
              w9[8] * (xp[sy2 * W + sx2] - m);
    tr[icl][xl] = f2bf(a * r * sc + bi);
  }
  __syncthreads();
  // vectorized NHWC store: 64 px x 64 ch, u16x8 per store
#pragma unroll
  for (int it2 = 0; it2 < 2; ++it2) {
    int s2 = it2 * 256 + t;          // 0..511
    int xl2 = s2 >> 3;               // 0..63
    int cg = s2 & 7;                 // 0..7
    u16x8 v;
#pragma unroll
    for (int j = 0; j < 8; j++) v[j] = tr[cg * 8 + j][xl2];
    *(u16x8*)&out[((size_t)((b * H + y) * W + xt * 64 + xl2)) * CDIM + icb * 64 + cg * 8] = v;
  }
}

// ---------------- 2x2 avg pool on NHWC bf16 (vectorized: 8 ch / thread) ----------------
__global__ __launch_bounds__(256) void k_pool_nhwc(const unsigned short* __restrict__ in,
                                                   unsigned short* __restrict__ out) {
  int i = blockIdx.x * 256 + threadIdx.x;   // < 4*64*64*32
  int cg = i & 31;
  int p = i >> 5;                            // (b*64+Y)*64+X
  int X = p & 63, Y = (p >> 6) & 63, b = p >> 12;
  const unsigned short* s =
      in + ((size_t)(b * 128 + 2 * Y) * 128 + 2 * X) * CDIM + cg * 8;
  u16x8 v0 = *(const u16x8*)(s);
  u16x8 v1 = *(const u16x8*)(s + CDIM);
  u16x8 v2 = *(const u16x8*)(s + 128 * CDIM);
  u16x8 v3 = *(const u16x8*)(s + 128 * CDIM + CDIM);
  u16x8 r;
#pragma unroll
  for (int j = 0; j < 8; j++)
    r[j] = f2bf(0.25f * (bf2f(v0[j]) + bf2f(v1[j]) + bf2f(v2[j]) + bf2f(v3[j])));
  *(u16x8*)(out + (size_t)p * CDIM + cg * 8) = r;
}

// ---------------- MFMA implicit-GEMM 3x3 reflect conv ----------------
// block 256 (4 waves) = 64 oc x (ROWS x W) pixel tile; wave = 64 oc x ROWS*W/4
// px (NF frags). x-halo-free LDS tile: reflect-pad columns are interior
// columns, resolved by per-lane col clamp at read time (no stored halo).
// ROWS=3 at hf raises wave FLOP/LDS-byte by 20% (cap 60%->72%); LDS 76.9KB
// keeps 2 blocks/CU anti-phased. Partial last y-tile predicated.
// 1D grid, XCD-chunked bijective swizzle. setprio around MFMA cluster.
template <int LW, int ROWS, bool DUAL, bool UPSB, bool NCHWOUT>
__global__ __launch_bounds__(256, 2) void k_conv_mfma(
    const unsigned short* __restrict__ srcA, const unsigned short* __restrict__ srcB,
    const unsigned short* __restrict__ wpkA, const unsigned short* __restrict__ wpkB,
    const float* __restrict__ bias, void* __restrict__ outp) {
  constexpr int W = 1 << LW, H = W, HW = W * W;
  constexpr int R = ROWS + 2;               // staged rows (1 halo row each side)
  constexpr int SLOTS = R * W;              // px slots in tin (x-halo-free)
  constexpr int NIT = SLOTS / 64;           // staging rounds (64 slots/round)
  constexpr int WPX = ROWS * W / 4;         // pixels per wave
  constexpr int NF = WPX / 16;              // 16-px fragments per wave
  constexpr int TILES_Y = (H + ROWS - 1) / ROWS;
  static_assert(SLOTS % 64 == 0, "slots");
  __shared__ __align__(16) unsigned short tin[SLOTS * 32];        // input tile, 32 ic
  __shared__ __align__(16) unsigned short wlds[9 * 4 * 64 * 8];   // 9 taps x 4 mi frags

  const int t = threadIdx.x;
  const int l = t & 63, wv = t >> 6;
  const int l15 = l & 15, l4 = l >> 4;

  // XCD-chunked bijective swizzle (nwg divisible by 8)
  const int hwid = blockIdx.x;
  const int nwg = gridDim.x;
  const int wk = (hwid & 7) * (nwg >> 3) + (hwid >> 3);
  const int mb = wk & 3;
  const int tidx = wk >> 2;
  const int ty = tidx % TILES_Y;
  const int b = tidx / TILES_Y;
  const int y0 = ty * ROWS;

  f32x4 acc[4][NF];
#pragma unroll
  for (int mi = 0; mi < 4; mi++)
#pragma unroll
    for (int nf = 0; nf < NF; nf++) acc[mi][nf] = (f32x4){0.f, 0.f, 0.f, 0.f};

  const int nsrc = DUAL ? 2 : 1;
  for (int src = 0; src < nsrc; ++src) {
    const unsigned short* ysrc = src ? srcB : srcA;
    const unsigned short* wpk = src ? wpkB : wpkA;
    const bool ups = UPSB && (src == 1);

    // hoist staging addresses out of the K loop
    const unsigned short* inptr[NIT];
#pragma unroll
    for (int it = 0; it < NIT; ++it) {
      int s = it * 64 + (t >> 2);        // slot
      int row = s >> LW;
      int col = s & (W - 1);
      int gy = refl(y0 - 1 + row, H);
      int sy, sx, sw;
      if (ups) { sy = gy >> 1; sx = col >> 1; sw = W >> 1; }
      else     { sy = gy;      sx = col;      sw = W; }
      int gsrc = (t & 3) ^ (col & 3);    // ic-slot XOR swizzle (source side)
      inptr[it] = ysrc + (((size_t)(b * sw + sy) * sw + sx) * CDIM + gsrc * 8);
    }
    const unsigned short* wsrc = wpk + ((size_t)(mb * 4 + wv) * 64 + l) * 8;

    for (int icc = 0; icc < 8; ++icc) {
      __syncthreads();
#pragma unroll
      for (int it = 0; it < NIT; ++it)
        gload_lds16(inptr[it] + icc * 32, &tin[(size_t)(it * 256 + t) * 8]);
#pragma unroll
      for (int tap = 0; tap < 9; ++tap)
        gload_lds16(wsrc + ((size_t)tap * 8 + (size_t)icc) * 8192,
                    &wlds[(size_t)(tap * 256 + t) * 8]);
      __syncthreads();

      __builtin_amdgcn_s_setprio(1);
#pragma unroll
      for (int tap = 0; tap < 9; ++tap) {
        const int dy = tap / 3, dx = tap - 3 * (tap / 3);
        bf16x8 af[4];
#pragma unroll
        for (int mi = 0; mi < 4; mi++)
          af[mi] = *(const bf16x8*)&wlds[(size_t)((tap * 4 + mi) * 64 + l) * 8];
#pragma unroll
        for (int nf = 0; nf < NF; nf++) {
          int pl = wv * WPX + nf * 16 + l15;
          int py = pl >> LW;
          int c = pl & (W - 1);
          int col = c + dx - 1;                       // reflect-pad via clamp
          col = col < 0 ? 1 : col;
          col = col > W - 1 ? W - 2 : col;
          int idx16 = ((py + dy) * W + col) * 4 + (l4 ^ (col & 3));
          bf16x8 bfv = *(const bf16x8*)&tin[(size_t)idx16 * 8];
#pragma unroll
          for (int mi = 0; mi < 4; mi++)
            acc[mi][nf] = __builtin_amdgcn_mfma_f32_16x16x32_bf16(af[mi], bfv, acc[mi][nf], 0, 0, 0);
        }
      }
      __builtin_amdgcn_s_setprio(0);
    }
  }

  // epilogue (skip rows past H on partial last tile)
#pragma unroll
  for (int mi = 0; mi < 4; mi++) {
    int oc0 = mb * 64 + mi * 16 + l4 * 4;
    float bv[4];
#pragma unroll
    for (int rr = 0; rr < 4; rr++) bv[rr] = bias ? bias[oc0 + rr] : 0.f;
#pragma unroll
    for (int nf = 0; nf < NF; nf++) {
      int pl = wv * WPX + nf * 16 + l15;
      int y = y0 + (pl >> LW);
      int x = pl & (W - 1);
      if (y >= H) continue;
      if (NCHWOUT) {
        float* o = (float*)outp;
#pragma unroll
        for (int rr = 0; rr < 4; rr++)
          o[((size_t)(b * CDIM + oc0 + rr)) * HW + y * W + x] = lrelu(acc[mi][nf][rr] + bv[rr]);
      } else {
        unsigned short* o = (unsigned short*)outp;
        ushort4 pk;
        pk.x = f2bf(lrelu(acc[mi][nf][0] + bv[0]));
        pk.y = f2bf(lrelu(acc[mi][nf][1] + bv[1]));
        pk.z = f2bf(lrelu(acc[mi][nf][2] + bv[2]));
        pk.w = f2bf(lrelu(acc[mi][nf][3] + bv[3]));
        *(ushort4*)&o[((size_t)((b * H + y) * W + x)) * CDIM + oc0] = pk;
      }
    }
  }
}

// ---------------- host ----------------
extern "C" void kernel_launch(void* const* d_in, const int* in_sizes, int n_in,
                              void* d_out, int out_size, void* d_ws, size_t ws_size,
                              hipStream_t stream) {
  (void)in_sizes; (void)n_in; (void)out_size;
  const float* c_hf = (const float*)d_in[0];
  const float* c_lf = (const float*)d_in[1];
  const float* s_hf = (const float*)d_in[2];
  const float* s_lf = (const float*)d_in[3];
  const float* h_sw = (const float*)d_in[4];
  const float* h_sb = (const float*)d_in[5];
  const float* h_pw = (const float*)d_in[6];
  const float* h_pb = (const float*)d_in[7];
  const float* h_bw = (const float*)d_in[8];
  const float* h_bb = (const float*)d_in[9];
  const float* l_sw = (const float*)d_in[10];
  const float* l_sb = (const float*)d_in[11];
  const float* l_pw = (const float*)d_in[12];
  const float* l_pb = (const float*)d_in[13];
  const float* l_bw = (const float*)d_in[14];
  const float* l_bb = (const float*)d_in[15];
  const float* ada_h_w = (const float*)d_in[16];
  const float* ada_h_b = (const float*)d_in[17];
  const float* ada_l_w = (const float*)d_in[18];
  const float* ada_l_b = (const float*)d_in[19];
  const float* h2h = (const float*)d_in[20];
  const float* l2h = (const float*)d_in[21];
  const float* h2l = (const float*)d_in[22];
  const float* l2l = (const float*)d_in[23];

  const int B = 4, H = 128, W = 128;

  float* base;
  size_t need = (size_t)TOTAL_F * sizeof(float);
  if (ws_size >= need) {
    base = (float*)d_ws;
  } else {
    void* p = nullptr;
    hipGetSymbolAddress(&p, HIP_SYMBOL(g_scratch));
    base = (float*)p;
  }

  float* ws_hf = base + OFF_WS_HF;
  float* ws_lf = base + OFF_WS_LF;
  float* wp_hf = base + OFF_WP_HF;
  float* bs_hf = base + OFF_BS_HF;
  float* wp_lf = base + OFF_WP_LF;
  float* bs_lf = base + OFF_BS_LF;
  float* mean_hf = base + OFF_MEAN_HF;
  float* rstd_hf = base + OFF_RSTD_HF;
  float* mean_lf = base + OFF_MEAN_LF;
  float* rstd_lf = base + OFF_RSTD_LF;
  unsigned short* u16 = (unsigned short*)(base + OFF_U16);
  unsigned short* yh = u16 + U_YH;
  unsigned short* yl = u16 + U_YL;
  unsigned short* hfA = u16 + U_HFA;
  unsigned short* lfA = u16 + U_LFA;
  unsigned short* hfP = u16 + U_HFP;
  unsigned short* pk      = u16 + U_PK;
  unsigned short* pk_adah = pk + 0 * PK_SZ;
  unsigned short* pk_h2h  = pk + 1 * PK_SZ;
  unsigned short* pk_l2h  = pk + 2 * PK_SZ;
  unsigned short* pk_adal = pk + 3 * PK_SZ;
  unsigned short* pk_l2l  = pk + 4 * PK_SZ;
  unsigned short* pk_h2l  = pk + 5 * PK_SZ;

  float* out_hf = (float*)d_out;
  float* out_lf = (float*)d_out + 16777216;

  // weight packing (6 matrices in one launch)
  k_packw6<<<dim3(2304, 6), dim3(256), 0, stream>>>(ada_h_w, h2h, l2h, ada_l_w, l2l, h2l, pk);

  // kernel_predict
  k_ws<<<dim3(B * CDIM), dim3(256), 0, stream>>>(s_hf, h_sw, h_sb, ws_hf);
  k_ws<<<dim3(B * CDIM), dim3(256), 0, stream>>>(s_lf, l_sw, l_sb, ws_lf);
  k_point<<<dim3(B), dim3(256), 0, stream>>>(s_hf, h_pw, h_pb, h_bw, h_bb, wp_hf, bs_hf);
  k_point<<<dim3(B), dim3(256), 0, stream>>>(s_lf, l_pw, l_pb, l_bw, l_bb, wp_lf, bs_lf);

  // instance norm stats
  k_istats<<<dim3(B * CDIM), dim3(256), 0, stream>>>(c_hf, mean_hf, rstd_hf, H * W);
  k_istats<<<dim3(B * CDIM), dim3(256), 0, stream>>>(c_lf, mean_lf, rstd_lf, (H / 2) * (W / 2));

  // fused IN + depthwise + pointwise -> NHWC bf16
  k_dwt<7><<<dim3(8, 128, 4), dim3(256), 0, stream>>>(c_hf, ws_hf, mean_hf, rstd_hf, wp_hf, bs_hf, yh);
  k_dwt<6><<<dim3(4, 64, 4), dim3(256), 0, stream>>>(c_lf, ws_lf, mean_lf, rstd_lf, wp_lf, bs_lf, yl);

  // ada convs (MFMA), bf16 NHWC out, lrelu.
  // hf: ROWS=3 -> 43 y-tiles (last partial), grid 4*43*4 = 688 (div by 8).
  k_conv_mfma<7, 3, false, false, false><<<dim3(688), dim3(256), 0, stream>>>(
      yh, nullptr, pk_adah, nullptr, ada_h_b, hfA);
  k_conv_mfma<6, 4, false, false, false><<<dim3(256), dim3(256), 0, stream>>>(
      yl, nullptr, pk_adal, nullptr, ada_l_b, lfA);

  // avgpool hf (vectorized)
  k_pool_nhwc<<<dim3(2048), dim3(256), 0, stream>>>(hfA, hfP);

  // fused output convs (MFMA), f32 NCHW out, lrelu
  k_conv_mfma<7, 3, true, true, true><<<dim3(688), dim3(256), 0, stream>>>(
      hfA, lfA, pk_h2h, pk_l2h, nullptr, out_hf);
  k_conv_mfma<6, 4, true, false, true><<<dim3(256), dim3(256), 0, stream>>>(
      lfA, hfP, pk_l2l, pk_h2l, nullptr, out_lf);
}

// Round 9
// 489.735 us; speedup vs baseline: 1.1622x; 1.0117x over previous
//
#include <hip/hip_runtime.h>
#include <hip/hip_bf16.h>

#define CDIM 256
#define EPS 1e-5f
#define SLOPE 0.01f

using f32x4  = __attribute__((ext_vector_type(4))) float;
typedef __bf16 bf16x8 __attribute__((ext_vector_type(8)));
typedef unsigned short u16x8 __attribute__((ext_vector_type(8)));

// ---------------- workspace layout ----------------
enum : size_t {
  OFF_WS_HF   = 0,
  OFF_WS_LF   = 9216,
  OFF_WP_HF   = 20480,
  OFF_BS_HF   = 21504,
  OFF_WP_LF   = 22528,
  OFF_BS_LF   = 23552,
  OFF_MEAN_HF = 24576,
  OFF_RSTD_HF = 25600,
  OFF_MEAN_LF = 26624,
  OFF_RSTD_LF = 27648,
  OFF_U16     = 32768,          // start of ushort region (float units)
};
// ushort offsets relative to u16 base
enum : size_t {
  U_YH  = 0,          // [4][128][128][256] bf16
  U_YL  = 16777216,   // [4][64][64][256]
  U_HFA = 20971520,   // [4][128][128][256]
  U_LFA = 37748736,   // [4][64][64][256]
  U_HFP = 41943040,   // [4][64][64][256]
  U_PK  = 46137344,   // 6 packed weights, each 589824
  PK_SZ = 589824,
  U_PKPH = U_PK + 6 * PK_SZ,    // phase-packed l2h: 4ph x 4tap x 8icc x 16mf x 64 x 8
  PH_SZ  = 1048576,
  U_END  = U_PKPH + PH_SZ,
};
// float phase buffer after the u16 region: [4][256][4][64][64] f32
enum : size_t {
  OFF_PHB = OFF_U16 + (U_END + 1) / 2,
  PHB_F   = 16777216,
  TOTAL_F = OFF_PHB + PHB_F,
};

__device__ float g_scratch[TOTAL_F];

__device__ __forceinline__ int refl(int q, int n) {
  return q < 0 ? -q : (q >= n ? 2 * n - 2 - q : q);
}
__device__ __forceinline__ float lrelu(float v) { return v >= 0.f ? v : SLOPE * v; }
__device__ __forceinline__ unsigned short f2bf(float f) {
  unsigned int u = __float_as_uint(f);
  u += 0x7fffu + ((u >> 16) & 1u);
  return (unsigned short)(u >> 16);
}
__device__ __forceinline__ float bf2f(unsigned short h) {
  return __uint_as_float(((unsigned int)h) << 16);
}
__device__ __forceinline__ void gload_lds16(const void* g, void* l) {
  __builtin_amdgcn_global_load_lds(
      (const __attribute__((address_space(1))) unsigned int*)g,
      (__attribute__((address_space(3))) unsigned int*)l, 16, 0, 0);
}

// ---------------- kernel_predict: spatial weights ----------------
__global__ __launch_bounds__(256) void k_ws(const float* __restrict__ s,
                                            const float* __restrict__ sw,
                                            const float* __restrict__ sb,
                                            float* __restrict__ ws_out) {
  int bo = blockIdx.x;
  int o = bo & (CDIM - 1);
  int c = threadIdx.x;
  int b = bo >> 8;
  float sv[9], wv[9];
  const float* sp = s + (size_t)(b * CDIM + c) * 9;
  const float* wp = sw + (size_t)(o * CDIM + c) * 9;
#pragma unroll
  for (int i = 0; i < 9; i++) { sv[i] = sp[i]; wv[i] = wp[i]; }
  float out9[9];
#pragma unroll
  for (int i = 0; i < 3; i++)
#pragma unroll
    for (int j = 0; j < 3; j++) {
      float a = 0.f;
#pragma unroll
      for (int dy = 0; dy < 3; dy++) {
        int u = i + dy - 1; u = (u < 0) ? 1 : (u > 2 ? 1 : u);
#pragma unroll
        for (int dx = 0; dx < 3; dx++) {
          int v = j + dx - 1; v = (v < 0) ? 1 : (v > 2 ? 1 : v);
          a += sv[u * 3 + v] * wv[dy * 3 + dx];
        }
      }
      out9[i * 3 + j] = a;
    }
  __shared__ float red[256 * 9];
#pragma unroll
  for (int i = 0; i < 9; i++) red[c * 9 + i] = out9[i];
  __syncthreads();
  for (int st = 128; st > 0; st >>= 1) {
    if (c < st)
#pragma unroll
      for (int i = 0; i < 9; i++) red[c * 9 + i] += red[(c + st) * 9 + i];
    __syncthreads();
  }
  if (c < 9) ws_out[(size_t)bo * 9 + c] = red[c] + sb[o];
}

// ---------------- pooled + w_point / bias (fused) ----------------
__global__ __launch_bounds__(256) void k_point(const float* __restrict__ s,
                                               const float* __restrict__ pw,
                                               const float* __restrict__ pb,
                                               const float* __restrict__ bw,
                                               const float* __restrict__ bb,
                                               float* __restrict__ wp_out,
                                               float* __restrict__ bs_out) {
  int b = blockIdx.x, o = threadIdx.x;
  __shared__ float pl[CDIM];
  const float* sp = s + (size_t)(b * CDIM + o) * 9;
  float a9 = 0.f;
#pragma unroll
  for (int j = 0; j < 9; j++) a9 += sp[j];
  pl[o] = a9 * (1.f / 9.f);
  __syncthreads();
  float a = pb[o], d = bb[o];
  for (int c = 0; c < CDIM; c++) {
    float p = pl[c];
    a += p * pw[o * CDIM + c];
    d += p * bw[o * CDIM + c];
  }
  wp_out[b * CDIM + o] = a;
  bs_out[b * CDIM + o] = d;
}

__global__ __launch_bounds__(256) void k_istats(const float* __restrict__ x,
                                                float* __restrict__ mean,
                                                float* __restrict__ rstd, int HW) {
  int plane = blockIdx.x;
  const float4* p = (const float4*)(x + (size_t)plane * HW);
  int n4 = HW >> 2;
  float s = 0.f, q = 0.f;
  for (int i = threadIdx.x; i < n4; i += 256) {
    float4 v = p[i];
    s += v.x + v.y + v.z + v.w;
    q += v.x * v.x + v.y * v.y + v.z * v.z + v.w * v.w;
  }
  __shared__ float rs[256], rq[256];
  rs[threadIdx.x] = s; rq[threadIdx.x] = q;
  __syncthreads();
  for (int st = 128; st > 0; st >>= 1) {
    if (threadIdx.x < st) {
      rs[threadIdx.x] += rs[threadIdx.x + st];
      rq[threadIdx.x] += rq[threadIdx.x + st];
    }
    __syncthreads();
  }
  if (threadIdx.x == 0) {
    float m = rs[0] / HW;
    float v = rq[0] / HW - m * m;
    mean[plane] = m;
    rstd[plane] = rsqrtf(v + EPS);
  }
}

// ---------------- weight pack: OIHW f32 -> [tap][icc][mf][lane][8] bf16 (6 mats) ----------------
__global__ void k_packw6(const float* __restrict__ w0, const float* __restrict__ w1,
                         const float* __restrict__ w2, const float* __restrict__ w3,
                         const float* __restrict__ w4, const float* __restrict__ w5,
                         unsigned short* __restrict__ pk) {
  const float* ws[6] = {w0, w1, w2, w3, w4, w5};
  int seg = blockIdx.y;
  const float* w = ws[seg];
  int i = blockIdx.x * 256 + threadIdx.x;   // < 589824
  int j = i & 7, l = (i >> 3) & 63, mf = (i >> 9) & 15, icc = (i >> 13) & 7, tap = i >> 16;
  int oc = mf * 16 + (l & 15);
  int ic = icc * 32 + (l >> 4) * 8 + j;
  pk[(size_t)seg * PK_SZ + i] = f2bf(w[((size_t)oc * 256 + ic) * 9 + tap]);
}

// ---------------- phase-collapsed l2h pack: up2-conv -> per-phase 2x2 taps ----------------
// W_ph[a][b][ty][tx] = sum_{dy in Sy(a,ty), dx in Sx(b,tx)} l2h[oc][ic][dy][dx]
// Sy(0,0)={0} Sy(0,1)={1,2} Sy(1,0)={0,1} Sy(1,1)={2}; same for x.
__global__ void k_packw_ph(const float* __restrict__ w, unsigned short* __restrict__ pk) {
  int i = blockIdx.x * 256 + threadIdx.x;   // < 1048576
  int j = i & 7, l = (i >> 3) & 63, mf = (i >> 9) & 15, icc = (i >> 13) & 7, tapph = i >> 16;
  int tap = tapph & 3, phase = tapph >> 2;
  int tx = tap & 1, ty = tap >> 1;
  int a = phase >> 1, bp = phase & 1;
  int oc = mf * 16 + (l & 15);
  int ic = icc * 32 + (l >> 4) * 8 + j;
  int ys = (a == 0) ? (ty == 0 ? 0 : 1) : (ty == 0 ? 0 : 2);
  int yc = (a == 0) ? (ty == 0 ? 1 : 2) : (ty == 0 ? 2 : 1);
  int xs = (bp == 0) ? (tx == 0 ? 0 : 1) : (tx == 0 ? 0 : 2);
  int xc = (bp == 0) ? (tx == 0 ? 1 : 2) : (tx == 0 ? 2 : 1);
  const float* wb = w + ((size_t)oc * 256 + ic) * 9;
  float acc = 0.f;
  for (int dy = ys; dy < ys + yc; dy++)
    for (int dx = xs; dx < xs + xc; dx++) acc += wb[dy * 3 + dx];
  pk[i] = f2bf(acc);
}

// ---------------- fused IN + dynamic depthwise + pointwise -> NHWC bf16 ----------------
template <int LW>
__global__ __launch_bounds__(256) void k_dwt(const float* __restrict__ x,
                                             const float* __restrict__ ws,
                                             const float* __restrict__ mean,
                                             const float* __restrict__ rstd,
                                             const float* __restrict__ wp,
                                             const float* __restrict__ bs,
                                             unsigned short* __restrict__ out) {
  constexpr int W = 1 << LW, H = W, HW = W * W;
  int t = threadIdx.x;
  int xt = (LW > 6) ? (blockIdx.x & ((W >> 6) - 1)) : 0;
  int icb = (LW > 6) ? (blockIdx.x >> (LW - 6)) : blockIdx.x;
  int y = blockIdx.y, b = blockIdx.z;
  __shared__ unsigned short tr[64][66];
  int xl = t & 63;
  int xx = xt * 64 + xl;
  int sy0 = refl(y - 1, H), sy1 = y, sy2 = refl(y + 1, H);
  int sx0 = refl(xx - 1, W), sx2 = refl(xx + 1, W);
#pragma unroll
  for (int rr = 0; rr < 16; ++rr) {
    int icl = rr * 4 + (t >> 6);
    int plane = b * CDIM + icb * 64 + icl;
    const float* xp = x + (size_t)plane * HW;
    float m = mean[plane], r = rstd[plane], sc = wp[plane], bi = bs[plane];
    const float* w9 = ws + (size_t)plane * 9;
    float a = w9[0] * (xp[sy0 * W + sx0] - m) + w9[1] * (xp[sy0 * W + xx] - m) +
              w9[2] * (xp[sy0 * W + sx2] - m) + w9[3] * (xp[sy1 * W + sx0] - m) +
              w9[4] * (xp[sy1 * W + xx] - m) + w9[5] * (xp[sy1 * W + sx2] - m) +
              w9[6] * (xp[sy2 * W + sx0] - m) + w9[7] * (xp[sy2 * W + xx] - m) +
              w9[8] * (xp[sy2 * W + sx2] - m);
    tr[icl][xl] = f2bf(a * r * sc + bi);
  }
  __syncthreads();
  // vectorized NHWC store: 64 px x 64 ch, u16x8 per store
#pragma unroll
  for (int it2 = 0; it2 < 2; ++it2) {
    int s2 = it2 * 256 + t;          // 0..511
    int xl2 = s2 >> 3;               // 0..63
    int cg = s2 & 7;                 // 0..7
    u16x8 v;
#pragma unroll
    for (int j = 0; j < 8; j++) v[j] = tr[cg * 8 + j][xl2];
    *(u16x8*)&out[((size_t)((b * H + y) * W + xt * 64 + xl2)) * CDIM + icb * 64 + cg * 8] = v;
  }
}

// ---------------- 2x2 avg pool on NHWC bf16 (vectorized: 8 ch / thread) ----------------
__global__ __launch_bounds__(256) void k_pool_nhwc(const unsigned short* __restrict__ in,
                                                   unsigned short* __restrict__ out) {
  int i = blockIdx.x * 256 + threadIdx.x;   // < 4*64*64*32
  int cg = i & 31;
  int p = i >> 5;                            // (b*64+Y)*64+X
  int X = p & 63, Y = (p >> 6) & 63, b = p >> 12;
  const unsigned short* s =
      in + ((size_t)(b * 128 + 2 * Y) * 128 + 2 * X) * CDIM + cg * 8;
  u16x8 v0 = *(const u16x8*)(s);
  u16x8 v1 = *(const u16x8*)(s + CDIM);
  u16x8 v2 = *(const u16x8*)(s + 128 * CDIM);
  u16x8 v3 = *(const u16x8*)(s + 128 * CDIM + CDIM);
  u16x8 r;
#pragma unroll
  for (int j = 0; j < 8; j++)
    r[j] = f2bf(0.25f * (bf2f(v0[j]) + bf2f(v1[j]) + bf2f(v2[j]) + bf2f(v3[j])));
  *(u16x8*)(out + (size_t)p * CDIM + cg * 8) = r;
}

// ---------------- MFMA implicit-GEMM 3x3 reflect conv (R5 structure + ACC) ----------------
// block 256 (4 waves), tile 64 oc x 256 pixels. Single-buffer, 2 barriers per
// icc-step, 2 blocks/CU anti-phased. ACC: fuse += phase-buffer (compact
// [b][oc][phase][64][64] f32) into the NCHW epilogue before lrelu.
template <int LW, bool DUAL, bool UPSB, bool NCHWOUT, bool ACC>
__global__ __launch_bounds__(256, 2) void k_conv_mfma(
    const unsigned short* __restrict__ srcA, const unsigned short* __restrict__ srcB,
    const unsigned short* __restrict__ wpkA, const unsigned short* __restrict__ wpkB,
    const float* __restrict__ bias, const float* __restrict__ accsrc,
    void* __restrict__ outp) {
  constexpr int W = 1 << LW, H = W, HW = W * W;
  constexpr int ROWS = 256 >> LW;       // pixel rows per block
  constexpr int R = ROWS + 2, Cw = W + 2;
  constexpr int RC = R * Cw;
  constexpr int RCPAD = (RC + 63) & ~63;
  constexpr int NIT = RCPAD / 64;
  __shared__ __align__(16) unsigned short tin[RCPAD * 32];        // input tile, 32 ic
  __shared__ __align__(16) unsigned short wlds[9 * 4 * 64 * 8];   // 9 taps x 4 mi frags

  const int t = threadIdx.x;
  const int l = t & 63, wv = t >> 6;
  const int l15 = l & 15, l4 = l >> 4;

  // XCD-chunked bijective swizzle (nwg divisible by 8)
  const int hwid = blockIdx.x;
  const int nwg = gridDim.x;
  const int wk = (hwid & 7) * (nwg >> 3) + (hwid >> 3);
  const int mb = wk & 3;
  const int pixbase = (wk >> 2) * 256;
  const int b = pixbase >> (2 * LW);
  const int y0 = (pixbase >> LW) & (H - 1);

  f32x4 acc[4][4];
#pragma unroll
  for (int mi = 0; mi < 4; mi++)
#pragma unroll
    for (int nf = 0; nf < 4; nf++) acc[mi][nf] = (f32x4){0.f, 0.f, 0.f, 0.f};

  const int nsrc = DUAL ? 2 : 1;
  for (int src = 0; src < nsrc; ++src) {
    const unsigned short* ysrc = src ? srcB : srcA;
    const unsigned short* wpk = src ? wpkB : wpkA;
    const bool ups = UPSB && (src == 1);

    // hoist staging addresses out of the K loop
    const unsigned short* inptr[NIT];
#pragma unroll
    for (int it = 0; it < NIT; ++it) {
      int rc = it * 64 + (t >> 2);
      int rcc = rc < RC - 1 ? rc : RC - 1;
      int r = rcc / Cw, tc = rcc - r * Cw;
      int gy = refl(y0 - 1 + r, H);
      int gx = refl(tc - 1, W);
      int sy, sx, sw;
      if (ups) { sy = gy >> 1; sx = gx >> 1; sw = W >> 1; }
      else     { sy = gy;      sx = gx;      sw = W; }
      int gsrc = (t & 3) ^ (tc & 3);   // ic-slot XOR swizzle (source side)
      inptr[it] = ysrc + (((size_t)(b * sw + sy) * sw + sx) * CDIM + gsrc * 8);
    }
    const unsigned short* wsrc = wpk + ((size_t)(mb * 4 + wv) * 64 + l) * 8;

    for (int icc = 0; icc < 8; ++icc) {
      __syncthreads();
#pragma unroll
      for (int it = 0; it < NIT; ++it)
        gload_lds16(inptr[it] + icc * 32, &tin[(size_t)(it * 256 + t) * 8]);
#pragma unroll
      for (int tap = 0; tap < 9; ++tap)
        gload_lds16(wsrc + ((size_t)tap * 8 + (size_t)icc) * 8192,
                    &wlds[(size_t)(tap * 256 + t) * 8]);
      __syncthreads();

      __builtin_amdgcn_s_setprio(1);
#pragma unroll
      for (int tap = 0; tap < 9; ++tap) {
        const int dy = tap / 3, dx = tap - 3 * (tap / 3);
        bf16x8 af[4];
#pragma unroll
        for (int mi = 0; mi < 4; mi++)
          af[mi] = *(const bf16x8*)&wlds[(size_t)((tap * 4 + mi) * 64 + l) * 8];
#pragma unroll
        for (int nf = 0; nf < 4; nf++) {
          int pl = wv * 64 + nf * 16 + l15;
          int py = pl >> LW;
          int c = pl & (W - 1);
          int tcol = c + dx;
          int idx16 = ((py + dy) * Cw + tcol) * 4 + (l4 ^ (tcol & 3));
          bf16x8 bfv = *(const bf16x8*)&tin[(size_t)idx16 * 8];
#pragma unroll
          for (int mi = 0; mi < 4; mi++)
            acc[mi][nf] = __builtin_amdgcn_mfma_f32_16x16x32_bf16(af[mi], bfv, acc[mi][nf], 0, 0, 0);
        }
      }
      __builtin_amdgcn_s_setprio(0);
    }
  }

  // epilogue
#pragma unroll
  for (int mi = 0; mi < 4; mi++) {
    int oc0 = mb * 64 + mi * 16 + l4 * 4;
    float bv[4];
#pragma unroll
    for (int rr = 0; rr < 4; rr++) bv[rr] = bias ? bias[oc0 + rr] : 0.f;
#pragma unroll
    for (int nf = 0; nf < 4; nf++) {
      int p = pixbase + wv * 64 + nf * 16 + l15;
      if (NCHWOUT) {
        float* o = (float*)outp;
        int pin = p & (HW - 1);
        int bb2 = p >> (2 * LW);
        int yy = pin >> LW, xx = pin & (W - 1);
        int ph = ((yy & 1) << 1) | (xx & 1);
        int q = (yy >> 1) * (W / 2) + (xx >> 1);
#pragma unroll
        for (int rr = 0; rr < 4; rr++) {
          float v = acc[mi][nf][rr] + bv[rr];
          if (ACC)
            v += accsrc[((size_t)(bb2 * CDIM + oc0 + rr) * 4 + ph) * (HW / 4) + q];
          o[((size_t)(bb2 * CDIM + oc0 + rr)) * HW + pin] = lrelu(v);
        }
      } else {
        unsigned short* o = (unsigned short*)outp;
        ushort4 pk;
        pk.x = f2bf(lrelu(acc[mi][nf][0] + bv[0]));
        pk.y = f2bf(lrelu(acc[mi][nf][1] + bv[1]));
        pk.z = f2bf(lrelu(acc[mi][nf][2] + bv[2]));
        pk.w = f2bf(lrelu(acc[mi][nf][3] + bv[3]));
        *(ushort4*)&o[(size_t)p * CDIM + oc0] = pk;
      }
    }
  }
}

// ---------------- phase-collapsed upsample-conv: 4-tap GEMM on lf grid ----------------
// out-phase (a,bp): out_hf[2Y+a, 2X+bp] += sum_{ty,tx} lf[clamp(Y-1+a+ty), clamp(X-1+bp+tx)] . Wph
// block = 64 oc x 256 lf-px (4 rows x 64 cols), one phase. Writes compact
// phase buffer [b][oc][phase][64][64] f32 (coalesced), consumed by h2h's ACC.
__global__ __launch_bounds__(256, 3) void k_conv_up(
    const unsigned short* __restrict__ lf, const unsigned short* __restrict__ wph,
    float* __restrict__ phb) {
  constexpr int NIT = 5;                      // 5 rows x 64 cols staged
  __shared__ __align__(16) unsigned short tin[320 * 64 / 2];      // 320 slots x 32ic x 2B
  __shared__ __align__(16) unsigned short wlds[4 * 256 * 8];      // 4 taps

  const int t = threadIdx.x;
  const int l = t & 63, wv = t >> 6;
  const int l15 = l & 15, l4 = l >> 4;

  const int hwid = blockIdx.x;
  const int wk = (hwid & 7) * 128 + (hwid >> 3);   // nwg = 1024
  const int mb = wk & 3;
  const int phase = (wk >> 2) & 3;
  const int tile = (wk >> 4) & 15;
  const int b = wk >> 8;
  const int a = phase >> 1, bp = phase & 1;
  const int Y0 = tile * 4;

  f32x4 acc[4][4];
#pragma unroll
  for (int mi = 0; mi < 4; mi++)
#pragma unroll
    for (int nf = 0; nf < 4; nf++) acc[mi][nf] = (f32x4){0.f, 0.f, 0.f, 0.f};

  const unsigned short* inptr[NIT];
#pragma unroll
  for (int it = 0; it < NIT; ++it) {
    int s = it * 64 + (t >> 2);
    int row = s >> 6, col = s & 63;
    int ly = Y0 - 1 + a + row;
    ly = ly < 0 ? 0 : (ly > 63 ? 63 : ly);
    int gsrc = (t & 3) ^ (col & 3);
    inptr[it] = lf + (((size_t)(b * 64 + ly) * 64 + col) * CDIM + gsrc * 8);
  }
  const unsigned short* wsrc = wph + ((size_t)(mb * 4 + wv) * 64 + l) * 8;

  for (int icc = 0; icc < 8; ++icc) {
    __syncthreads();
#pragma unroll
    for (int it = 0; it < NIT; ++it)
      gload_lds16(inptr[it] + icc * 32, &tin[(size_t)(it * 256 + t) * 8]);
#pragma unroll
    for (int tap = 0; tap < 4; ++tap)
      gload_lds16(wsrc + ((size_t)(phase * 4 + tap) * 8 + (size_t)icc) * 8192,
                  &wlds[(size_t)(tap * 256 + t) * 8]);
    __syncthreads();

    __builtin_amdgcn_s_setprio(1);
#pragma unroll
    for (int tap = 0; tap < 4; ++tap) {
      const int ty = tap >> 1, tx = tap & 1;
      bf16x8 af[4];
#pragma unroll
      for (int mi = 0; mi < 4; mi++)
        af[mi] = *(const bf16x8*)&wlds[(size_t)((tap * 4 + mi) * 64 + l) * 8];
#pragma unroll
      for (int nf = 0; nf < 4; nf++) {
        int pl = wv * 64 + nf * 16 + l15;
        int py = pl >> 6;
        int col = pl & 63;
        int tcol = col - 1 + bp + tx;
        tcol = tcol < 0 ? 0 : (tcol > 63 ? 63 : tcol);
        int idx16 = ((py + ty) * 64 + tcol) * 4 + (l4 ^ (tcol & 3));
        bf16x8 bfv = *(const bf16x8*)&tin[(size_t)idx16 * 8];
#pragma unroll
        for (int mi = 0; mi < 4; mi++)
          acc[mi][nf] = __builtin_amdgcn_mfma_f32_16x16x32_bf16(af[mi], bfv, acc[mi][nf], 0, 0, 0);
      }
    }
    __builtin_amdgcn_s_setprio(0);
  }

  // coalesced write into phase buffer
#pragma unroll
  for (int mi = 0; mi < 4; mi++) {
    int oc0 = mb * 64 + mi * 16 + l4 * 4;
#pragma unroll
    for (int nf = 0; nf < 4; nf++) {
      int pl = wv * 64 + nf * 16 + l15;
      int py = pl >> 6, col = pl & 63;
      size_t base = ((size_t)(b * CDIM + oc0) * 4 + phase) * 4096 + (Y0 + py) * 64 + col;
#pragma unroll
      for (int rr = 0; rr < 4; rr++)
        phb[base + (size_t)rr * 4 * 4096] = acc[mi][nf][rr];
    }
  }
}

// ---------------- host ----------------
extern "C" void kernel_launch(void* const* d_in, const int* in_sizes, int n_in,
                              void* d_out, int out_size, void* d_ws, size_t ws_size,
                              hipStream_t stream) {
  (void)in_sizes; (void)n_in; (void)out_size;
  const float* c_hf = (const float*)d_in[0];
  const float* c_lf = (const float*)d_in[1];
  const float* s_hf = (const float*)d_in[2];
  const float* s_lf = (const float*)d_in[3];
  const float* h_sw = (const float*)d_in[4];
  const float* h_sb = (const float*)d_in[5];
  const float* h_pw = (const float*)d_in[6];
  const float* h_pb = (const float*)d_in[7];
  const float* h_bw = (const float*)d_in[8];
  const float* h_bb = (const float*)d_in[9];
  const float* l_sw = (const float*)d_in[10];
  const float* l_sb = (const float*)d_in[11];
  const float* l_pw = (const float*)d_in[12];
  const float* l_pb = (const float*)d_in[13];
  const float* l_bw = (const float*)d_in[14];
  const float* l_bb = (const float*)d_in[15];
  const float* ada_h_w = (const float*)d_in[16];
  const float* ada_h_b = (const float*)d_in[17];
  const float* ada_l_w = (const float*)d_in[18];
  const float* ada_l_b = (const float*)d_in[19];
  const float* h2h = (const float*)d_in[20];
  const float* l2h = (const float*)d_in[21];
  const float* h2l = (const float*)d_in[22];
  const float* l2l = (const float*)d_in[23];

  const int B = 4, H = 128, W = 128;

  float* base;
  size_t need = (size_t)TOTAL_F * sizeof(float);
  if (ws_size >= need) {
    base = (float*)d_ws;
  } else {
    void* p = nullptr;
    hipGetSymbolAddress(&p, HIP_SYMBOL(g_scratch));
    base = (float*)p;
  }

  float* ws_hf = base + OFF_WS_HF;
  float* ws_lf = base + OFF_WS_LF;
  float* wp_hf = base + OFF_WP_HF;
  float* bs_hf = base + OFF_BS_HF;
  float* wp_lf = base + OFF_WP_LF;
  float* bs_lf = base + OFF_BS_LF;
  float* mean_hf = base + OFF_MEAN_HF;
  float* rstd_hf = base + OFF_RSTD_HF;
  float* mean_lf = base + OFF_MEAN_LF;
  float* rstd_lf = base + OFF_RSTD_LF;
  float* phb     = base + OFF_PHB;
  unsigned short* u16 = (unsigned short*)(base + OFF_U16);
  unsigned short* yh = u16 + U_YH;
  unsigned short* yl = u16 + U_YL;
  unsigned short* hfA = u16 + U_HFA;
  unsigned short* lfA = u16 + U_LFA;
  unsigned short* hfP = u16 + U_HFP;
  unsigned short* pk      = u16 + U_PK;
  unsigned short* pk_adah = pk + 0 * PK_SZ;
  unsigned short* pk_h2h  = pk + 1 * PK_SZ;
  unsigned short* pk_adal = pk + 3 * PK_SZ;
  unsigned short* pk_l2l  = pk + 4 * PK_SZ;
  unsigned short* pk_h2l  = pk + 5 * PK_SZ;
  unsigned short* pk_ph   = u16 + U_PKPH;

  float* out_hf = (float*)d_out;
  float* out_lf = (float*)d_out + 16777216;

  // weight packing
  k_packw6<<<dim3(2304, 6), dim3(256), 0, stream>>>(ada_h_w, h2h, l2h, ada_l_w, l2l, h2l, pk);
  k_packw_ph<<<dim3(4096), dim3(256), 0, stream>>>(l2h, pk_ph);

  // kernel_predict
  k_ws<<<dim3(B * CDIM), dim3(256), 0, stream>>>(s_hf, h_sw, h_sb, ws_hf);
  k_ws<<<dim3(B * CDIM), dim3(256), 0, stream>>>(s_lf, l_sw, l_sb, ws_lf);
  k_point<<<dim3(B), dim3(256), 0, stream>>>(s_hf, h_pw, h_pb, h_bw, h_bb, wp_hf, bs_hf);
  k_point<<<dim3(B), dim3(256), 0, stream>>>(s_lf, l_pw, l_pb, l_bw, l_bb, wp_lf, bs_lf);

  // instance norm stats
  k_istats<<<dim3(B * CDIM), dim3(256), 0, stream>>>(c_hf, mean_hf, rstd_hf, H * W);
  k_istats<<<dim3(B * CDIM), dim3(256), 0, stream>>>(c_lf, mean_lf, rstd_lf, (H / 2) * (W / 2));

  // fused IN + depthwise + pointwise -> NHWC bf16
  k_dwt<7><<<dim3(8, 128, 4), dim3(256), 0, stream>>>(c_hf, ws_hf, mean_hf, rstd_hf, wp_hf, bs_hf, yh);
  k_dwt<6><<<dim3(4, 64, 4), dim3(256), 0, stream>>>(c_lf, ws_lf, mean_lf, rstd_lf, wp_lf, bs_lf, yl);

  // ada convs (MFMA), bf16 NHWC out, lrelu
  k_conv_mfma<7, false, false, false, false><<<dim3(1024), dim3(256), 0, stream>>>(
      yh, nullptr, pk_adah, nullptr, ada_h_b, nullptr, hfA);
  k_conv_mfma<6, false, false, false, false><<<dim3(256), dim3(256), 0, stream>>>(
      yl, nullptr, pk_adal, nullptr, ada_l_b, nullptr, lfA);

  // avgpool hf (vectorized)
  k_pool_nhwc<<<dim3(2048), dim3(256), 0, stream>>>(hfA, hfP);

  // hf_out = lrelu(conv(hf,h2h) + phase-collapsed conv(up(lf),l2h))
  k_conv_up<<<dim3(1024), dim3(256), 0, stream>>>(lfA, pk_ph, phb);
  k_conv_mfma<7, false, false, true, true><<<dim3(1024), dim3(256), 0, stream>>>(
      hfA, nullptr, pk_h2h, nullptr, nullptr, phb, out_hf);

  // lf_out = lrelu(conv(lf,l2l) + conv(avgpool2(hf),h2l))
  k_conv_mfma<6, true, false, true, false><<<dim3(256), dim3(256), 0, stream>>>(
      lfA, hfP, pk_l2l, pk_h2l, nullptr, nullptr, out_lf);
}

// Round 10
// 460.085 us; speedup vs baseline: 1.2371x; 1.0644x over previous
//
#include <hip/hip_runtime.h>
#include <hip/hip_bf16.h>

#define CDIM 256
#define EPS 1e-5f
#define SLOPE 0.01f

using f32x4  = __attribute__((ext_vector_type(4))) float;
typedef __bf16 bf16x8 __attribute__((ext_vector_type(8)));
typedef unsigned short u16x8 __attribute__((ext_vector_type(8)));

// ---------------- workspace layout ----------------
enum : size_t {
  OFF_WS_HF   = 0,
  OFF_WS_LF   = 9216,
  OFF_WP_HF   = 20480,
  OFF_BS_HF   = 21504,
  OFF_WP_LF   = 22528,
  OFF_BS_LF   = 23552,
  OFF_MEAN_HF = 24576,
  OFF_RSTD_HF = 25600,
  OFF_MEAN_LF = 26624,
  OFF_RSTD_LF = 27648,
  OFF_U16     = 32768,          // start of ushort region (float units)
};
// ushort offsets relative to u16 base
enum : size_t {
  U_YH  = 0,          // [4][128][128][256] bf16
  U_YL  = 16777216,   // [4][64][64][256]
  U_HFA = 20971520,   // [4][128][128][256]
  U_LFA = 37748736,   // [4][64][64][256]
  U_HFP = 41943040,   // [4][64][64][256]
  U_PK  = 46137344,   // 6 packed weight slots, each 589824 (slot2 unused)
  PK_SZ = 589824,
  U_PKPH = U_PK + 6 * PK_SZ,    // phase-packed l2h: 4ph x 4tap x 8icc x 16mf x 64 x 8
  PH_SZ  = 1048576,
  U_PHB  = U_PKPH + PH_SZ,      // phase buffer [4][256][4][64][64] bf16
  U_END  = U_PHB + 16777216,
};
enum : size_t { TOTAL_F = OFF_U16 + (U_END + 1) / 2 };

__device__ float g_scratch[TOTAL_F];

__device__ __forceinline__ int refl(int q, int n) {
  return q < 0 ? -q : (q >= n ? 2 * n - 2 - q : q);
}
__device__ __forceinline__ float lrelu(float v) { return v >= 0.f ? v : SLOPE * v; }
__device__ __forceinline__ unsigned short f2bf(float f) {
  unsigned int u = __float_as_uint(f);
  u += 0x7fffu + ((u >> 16) & 1u);
  return (unsigned short)(u >> 16);
}
__device__ __forceinline__ float bf2f(unsigned short h) {
  return __uint_as_float(((unsigned int)h) << 16);
}
__device__ __forceinline__ void gload_lds16(const void* g, void* l) {
  __builtin_amdgcn_global_load_lds(
      (const __attribute__((address_space(1))) unsigned int*)g,
      (__attribute__((address_space(3))) unsigned int*)l, 16, 0, 0);
}

// ---------------- kernel_predict: spatial weights (hf & lf in one launch) ----------------
__global__ __launch_bounds__(256) void k_ws(const float* __restrict__ s_hf,
                                            const float* __restrict__ sw_hf,
                                            const float* __restrict__ sb_hf,
                                            float* __restrict__ ws_hf,
                                            const float* __restrict__ s_lf,
                                            const float* __restrict__ sw_lf,
                                            const float* __restrict__ sb_lf,
                                            float* __restrict__ ws_lf) {
  const bool lf = blockIdx.y != 0;
  const float* s  = lf ? s_lf : s_hf;
  const float* sw = lf ? sw_lf : sw_hf;
  const float* sb = lf ? sb_lf : sb_hf;
  float* ws_out   = lf ? ws_lf : ws_hf;
  int bo = blockIdx.x;
  int o = bo & (CDIM - 1);
  int c = threadIdx.x;
  int b = bo >> 8;
  float sv[9], wv[9];
  const float* sp = s + (size_t)(b * CDIM + c) * 9;
  const float* wp = sw + (size_t)(o * CDIM + c) * 9;
#pragma unroll
  for (int i = 0; i < 9; i++) { sv[i] = sp[i]; wv[i] = wp[i]; }
  float out9[9];
#pragma unroll
  for (int i = 0; i < 3; i++)
#pragma unroll
    for (int j = 0; j < 3; j++) {
      float a = 0.f;
#pragma unroll
      for (int dy = 0; dy < 3; dy++) {
        int u = i + dy - 1; u = (u < 0) ? 1 : (u > 2 ? 1 : u);
#pragma unroll
        for (int dx = 0; dx < 3; dx++) {
          int v = j + dx - 1; v = (v < 0) ? 1 : (v > 2 ? 1 : v);
          a += sv[u * 3 + v] * wv[dy * 3 + dx];
        }
      }
      out9[i * 3 + j] = a;
    }
  __shared__ float red[256 * 9];
#pragma unroll
  for (int i = 0; i < 9; i++) red[c * 9 + i] = out9[i];
  __syncthreads();
  for (int st = 128; st > 0; st >>= 1) {
    if (c < st)
#pragma unroll
      for (int i = 0; i < 9; i++) red[c * 9 + i] += red[(c + st) * 9 + i];
    __syncthreads();
  }
  if (c < 9) ws_out[(size_t)bo * 9 + c] = red[c] + sb[o];
}

// ---------------- pooled + w_point / bias (hf & lf in one launch, float4) ----------------
__global__ __launch_bounds__(256) void k_point(const float* __restrict__ s_hf,
                                               const float* __restrict__ pw_hf,
                                               const float* __restrict__ pb_hf,
                                               const float* __restrict__ bw_hf,
                                               const float* __restrict__ bb_hf,
                                               float* __restrict__ wp_hf,
                                               float* __restrict__ bs_hf,
                                               const float* __restrict__ s_lf,
                                               const float* __restrict__ pw_lf,
                                               const float* __restrict__ pb_lf,
                                               const float* __restrict__ bw_lf,
                                               const float* __restrict__ bb_lf,
                                               float* __restrict__ wp_lf,
                                               float* __restrict__ bs_lf) {
  const bool lf = blockIdx.y != 0;
  const float* s  = lf ? s_lf : s_hf;
  const float* pw = lf ? pw_lf : pw_hf;
  const float* pb = lf ? pb_lf : pb_hf;
  const float* bw = lf ? bw_lf : bw_hf;
  const float* bb = lf ? bb_lf : bb_hf;
  float* wp_out = lf ? wp_lf : wp_hf;
  float* bs_out = lf ? bs_lf : bs_hf;
  int b = blockIdx.x, o = threadIdx.x;
  __shared__ float pl[CDIM];
  const float* sp = s + (size_t)(b * CDIM + o) * 9;
  float a9 = 0.f;
#pragma unroll
  for (int j = 0; j < 9; j++) a9 += sp[j];
  pl[o] = a9 * (1.f / 9.f);
  __syncthreads();
  float a = pb[o], d = bb[o];
  const float4* pw4 = (const float4*)(pw + (size_t)o * CDIM);
  const float4* bw4 = (const float4*)(bw + (size_t)o * CDIM);
  const float4* pl4 = (const float4*)pl;
  for (int c4 = 0; c4 < CDIM / 4; c4++) {
    float4 p = pl4[c4];
    float4 w1 = pw4[c4], w2 = bw4[c4];
    a += p.x * w1.x + p.y * w1.y + p.z * w1.z + p.w * w1.w;
    d += p.x * w2.x + p.y * w2.y + p.z * w2.z + p.w * w2.w;
  }
  wp_out[b * CDIM + o] = a;
  bs_out[b * CDIM + o] = d;
}

// ---------------- instance norm stats (hf & lf in one launch) ----------------
__global__ __launch_bounds__(256) void k_istats(const float* __restrict__ xh,
                                                float* __restrict__ mh, float* __restrict__ rh,
                                                const float* __restrict__ xl,
                                                float* __restrict__ ml, float* __restrict__ rl) {
  const bool lf = blockIdx.x >= 1024;
  int plane = lf ? blockIdx.x - 1024 : blockIdx.x;
  const float* x = lf ? xl : xh;
  float* mean = lf ? ml : mh;
  float* rstd = lf ? rl : rh;
  const int HW = lf ? 4096 : 16384;
  const float4* p = (const float4*)(x + (size_t)plane * HW);
  int n4 = HW >> 2;
  float s = 0.f, q = 0.f;
  for (int i = threadIdx.x; i < n4; i += 256) {
    float4 v = p[i];
    s += v.x + v.y + v.z + v.w;
    q += v.x * v.x + v.y * v.y + v.z * v.z + v.w * v.w;
  }
  __shared__ float rs[256], rq[256];
  rs[threadIdx.x] = s; rq[threadIdx.x] = q;
  __syncthreads();
  for (int st = 128; st > 0; st >>= 1) {
    if (threadIdx.x < st) {
      rs[threadIdx.x] += rs[threadIdx.x + st];
      rq[threadIdx.x] += rq[threadIdx.x + st];
    }
    __syncthreads();
  }
  if (threadIdx.x == 0) {
    float m = rs[0] / HW;
    float v = rq[0] / HW - m * m;
    mean[plane] = m;
    rstd[plane] = rsqrtf(v + EPS);
  }
}

// ---------------- all weight packing in one launch ----------------
// seg 0..4: OIHW f32 -> [tap][icc][mf][lane][8] bf16 (ada_h, h2h, ada_l, l2l, h2l)
// seg 5: phase-collapsed l2h (up2-conv -> per-phase 2x2 taps)
__global__ void k_packall(const float* __restrict__ w_adah, const float* __restrict__ w_h2h,
                          const float* __restrict__ w_adal, const float* __restrict__ w_l2l,
                          const float* __restrict__ w_h2l, const float* __restrict__ w_l2h,
                          unsigned short* __restrict__ pk, unsigned short* __restrict__ pkph) {
  int seg = blockIdx.y;
  int i = blockIdx.x * 256 + threadIdx.x;
  if (seg < 5) {
    if (i >= 589824) return;
    const float* srcs[5] = {w_adah, w_h2h, w_adal, w_l2l, w_h2l};
    const int slot[5] = {0, 1, 3, 4, 5};
    const float* w = srcs[seg];
    int j = i & 7, l = (i >> 3) & 63, mf = (i >> 9) & 15, icc = (i >> 13) & 7, tap = i >> 16;
    int oc = mf * 16 + (l & 15);
    int ic = icc * 32 + (l >> 4) * 8 + j;
    pk[(size_t)slot[seg] * PK_SZ + i] = f2bf(w[((size_t)oc * 256 + ic) * 9 + tap]);
  } else {
    // phase pack: i < 1048576
    int j = i & 7, l = (i >> 3) & 63, mf = (i >> 9) & 15, icc = (i >> 13) & 7, tapph = i >> 16;
    int tap = tapph & 3, phase = tapph >> 2;
    int tx = tap & 1, ty = tap >> 1;
    int a = phase >> 1, bp = phase & 1;
    int oc = mf * 16 + (l & 15);
    int ic = icc * 32 + (l >> 4) * 8 + j;
    int ys = (a == 0) ? (ty == 0 ? 0 : 1) : (ty == 0 ? 0 : 2);
    int yc = (a == 0) ? (ty == 0 ? 1 : 2) : (ty == 0 ? 2 : 1);
    int xs = (bp == 0) ? (tx == 0 ? 0 : 1) : (tx == 0 ? 0 : 2);
    int xc = (bp == 0) ? (tx == 0 ? 1 : 2) : (tx == 0 ? 2 : 1);
    const float* wb = w_l2h + ((size_t)oc * 256 + ic) * 9;
    float acc = 0.f;
    for (int dy = ys; dy < ys + yc; dy++)
      for (int dx = xs; dx < xs + xc; dx++) acc += wb[dy * 3 + dx];
    pkph[i] = f2bf(acc);
  }
}

// ---------------- fused IN + dynamic depthwise + pointwise -> NHWC bf16 ----------------
template <int LW>
__global__ __launch_bounds__(256) void k_dwt(const float* __restrict__ x,
                                             const float* __restrict__ ws,
                                             const float* __restrict__ mean,
                                             const float* __restrict__ rstd,
                                             const float* __restrict__ wp,
                                             const float* __restrict__ bs,
                                             unsigned short* __restrict__ out) {
  constexpr int W = 1 << LW, H = W, HW = W * W;
  int t = threadIdx.x;
  int xt = (LW > 6) ? (blockIdx.x & ((W >> 6) - 1)) : 0;
  int icb = (LW > 6) ? (blockIdx.x >> (LW - 6)) : blockIdx.x;
  int y = blockIdx.y, b = blockIdx.z;
  __shared__ unsigned short tr[64][66];
  int xl = t & 63;
  int xx = xt * 64 + xl;
  int sy0 = refl(y - 1, H), sy1 = y, sy2 = refl(y + 1, H);
  int sx0 = refl(xx - 1, W), sx2 = refl(xx + 1, W);
#pragma unroll
  for (int rr = 0; rr < 16; ++rr) {
    int icl = rr * 4 + (t >> 6);
    int plane = b * CDIM + icb * 64 + icl;
    const float* xp = x + (size_t)plane * HW;
    float m = mean[plane], r = rstd[plane], sc = wp[plane], bi = bs[plane];
    const float* w9 = ws + (size_t)plane * 9;
    float a = w9[0] * (xp[sy0 * W + sx0] - m) + w9[1] * (xp[sy0 * W + xx] - m) +
              w9[2] * (xp[sy0 * W + sx2] - m) + w9[3] * (xp[sy1 * W + sx0] - m) +
              w9[4] * (xp[sy1 * W + xx] - m) + w9[5] * (xp[sy1 * W + sx2] - m) +
              w9[6] * (xp[sy2 * W + sx0] - m) + w9[7] * (xp[sy2 * W + xx] - m) +
              w9[8] * (xp[sy2 * W + sx2] - m);
    tr[icl][xl] = f2bf(a * r * sc + bi);
  }
  __syncthreads();
  // vectorized NHWC store: 64 px x 64 ch, u16x8 per store
#pragma unroll
  for (int it2 = 0; it2 < 2; ++it2) {
    int s2 = it2 * 256 + t;          // 0..511
    int xl2 = s2 >> 3;               // 0..63
    int cg = s2 & 7;                 // 0..7
    u16x8 v;
#pragma unroll
    for (int j = 0; j < 8; j++) v[j] = tr[cg * 8 + j][xl2];
    *(u16x8*)&out[((size_t)((b * H + y) * W + xt * 64 + xl2)) * CDIM + icb * 64 + cg * 8] = v;
  }
}

// ---------------- 2x2 avg pool on NHWC bf16 (vectorized: 8 ch / thread) ----------------
__global__ __launch_bounds__(256) void k_pool_nhwc(const unsigned short* __restrict__ in,
                                                   unsigned short* __restrict__ out) {
  int i = blockIdx.x * 256 + threadIdx.x;   // < 4*64*64*32
  int cg = i & 31;
  int p = i >> 5;                            // (b*64+Y)*64+X
  int X = p & 63, Y = (p >> 6) & 63, b = p >> 12;
  const unsigned short* s =
      in + ((size_t)(b * 128 + 2 * Y) * 128 + 2 * X) * CDIM + cg * 8;
  u16x8 v0 = *(const u16x8*)(s);
  u16x8 v1 = *(const u16x8*)(s + CDIM);
  u16x8 v2 = *(const u16x8*)(s + 128 * CDIM);
  u16x8 v3 = *(const u16x8*)(s + 128 * CDIM + CDIM);
  u16x8 r;
#pragma unroll
  for (int j = 0; j < 8; j++)
    r[j] = f2bf(0.25f * (bf2f(v0[j]) + bf2f(v1[j]) + bf2f(v2[j]) + bf2f(v3[j])));
  *(u16x8*)(out + (size_t)p * CDIM + cg * 8) = r;
}

// ---------------- MFMA implicit-GEMM 3x3 reflect conv (R5 structure + ACC) ----------------
// block 256 (4 waves), tile 64 oc x 256 pixels. Single-buffer, 2 barriers per
// icc-step, 2 blocks/CU anti-phased. ACC: fuse += bf16 phase-buffer
// ([b][oc][phase][64][64]) into the NCHW epilogue before lrelu.
template <int LW, bool DUAL, bool UPSB, bool NCHWOUT, bool ACC>
__global__ __launch_bounds__(256, 2) void k_conv_mfma(
    const unsigned short* __restrict__ srcA, const unsigned short* __restrict__ srcB,
    const unsigned short* __restrict__ wpkA, const unsigned short* __restrict__ wpkB,
    const float* __restrict__ bias, const unsigned short* __restrict__ accsrc,
    void* __restrict__ outp) {
  constexpr int W = 1 << LW, H = W, HW = W * W;
  constexpr int ROWS = 256 >> LW;       // pixel rows per block
  constexpr int R = ROWS + 2, Cw = W + 2;
  constexpr int RC = R * Cw;
  constexpr int RCPAD = (RC + 63) & ~63;
  constexpr int NIT = RCPAD / 64;
  __shared__ __align__(16) unsigned short tin[RCPAD * 32];        // input tile, 32 ic
  __shared__ __align__(16) unsigned short wlds[9 * 4 * 64 * 8];   // 9 taps x 4 mi frags

  const int t = threadIdx.x;
  const int l = t & 63, wv = t >> 6;
  const int l15 = l & 15, l4 = l >> 4;

  // XCD-chunked bijective swizzle (nwg divisible by 8)
  const int hwid = blockIdx.x;
  const int nwg = gridDim.x;
  const int wk = (hwid & 7) * (nwg >> 3) + (hwid >> 3);
  const int mb = wk & 3;
  const int pixbase = (wk >> 2) * 256;
  const int b = pixbase >> (2 * LW);
  const int y0 = (pixbase >> LW) & (H - 1);

  f32x4 acc[4][4];
#pragma unroll
  for (int mi = 0; mi < 4; mi++)
#pragma unroll
    for (int nf = 0; nf < 4; nf++) acc[mi][nf] = (f32x4){0.f, 0.f, 0.f, 0.f};

  const int nsrc = DUAL ? 2 : 1;
  for (int src = 0; src < nsrc; ++src) {
    const unsigned short* ysrc = src ? srcB : srcA;
    const unsigned short* wpk = src ? wpkB : wpkA;
    const bool ups = UPSB && (src == 1);

    // hoist staging addresses out of the K loop
    const unsigned short* inptr[NIT];
#pragma unroll
    for (int it = 0; it < NIT; ++it) {
      int rc = it * 64 + (t >> 2);
      int rcc = rc < RC - 1 ? rc : RC - 1;
      int r = rcc / Cw, tc = rcc - r * Cw;
      int gy = refl(y0 - 1 + r, H);
      int gx = refl(tc - 1, W);
      int sy, sx, sw;
      if (ups) { sy = gy >> 1; sx = gx >> 1; sw = W >> 1; }
      else     { sy = gy;      sx = gx;      sw = W; }
      int gsrc = (t & 3) ^ (tc & 3);   // ic-slot XOR swizzle (source side)
      inptr[it] = ysrc + (((size_t)(b * sw + sy) * sw + sx) * CDIM + gsrc * 8);
    }
    const unsigned short* wsrc = wpk + ((size_t)(mb * 4 + wv) * 64 + l) * 8;

    for (int icc = 0; icc < 8; ++icc) {
      __syncthreads();
#pragma unroll
      for (int it = 0; it < NIT; ++it)
        gload_lds16(inptr[it] + icc * 32, &tin[(size_t)(it * 256 + t) * 8]);
#pragma unroll
      for (int tap = 0; tap < 9; ++tap)
        gload_lds16(wsrc + ((size_t)tap * 8 + (size_t)icc) * 8192,
                    &wlds[(size_t)(tap * 256 + t) * 8]);
      __syncthreads();

      __builtin_amdgcn_s_setprio(1);
#pragma unroll
      for (int tap = 0; tap < 9; ++tap) {
        const int dy = tap / 3, dx = tap - 3 * (tap / 3);
        bf16x8 af[4];
#pragma unroll
        for (int mi = 0; mi < 4; mi++)
          af[mi] = *(const bf16x8*)&wlds[(size_t)((tap * 4 + mi) * 64 + l) * 8];
#pragma unroll
        for (int nf = 0; nf < 4; nf++) {
          int pl = wv * 64 + nf * 16 + l15;
          int py = pl >> LW;
          int c = pl & (W - 1);
          int tcol = c + dx;
          int idx16 = ((py + dy) * Cw + tcol) * 4 + (l4 ^ (tcol & 3));
          bf16x8 bfv = *(const bf16x8*)&tin[(size_t)idx16 * 8];
#pragma unroll
          for (int mi = 0; mi < 4; mi++)
            acc[mi][nf] = __builtin_amdgcn_mfma_f32_16x16x32_bf16(af[mi], bfv, acc[mi][nf], 0, 0, 0);
        }
      }
      __builtin_amdgcn_s_setprio(0);
    }
  }

  // epilogue
#pragma unroll
  for (int mi = 0; mi < 4; mi++) {
    int oc0 = mb * 64 + mi * 16 + l4 * 4;
    float bv[4];
#pragma unroll
    for (int rr = 0; rr < 4; rr++) bv[rr] = bias ? bias[oc0 + rr] : 0.f;
#pragma unroll
    for (int nf = 0; nf < 4; nf++) {
      int p = pixbase + wv * 64 + nf * 16 + l15;
      if (NCHWOUT) {
        float* o = (float*)outp;
        int pin = p & (HW - 1);
        int bb2 = p >> (2 * LW);
        int yy = pin >> LW, xx = pin & (W - 1);
        int ph = ((yy & 1) << 1) | (xx & 1);
        int q = (yy >> 1) * (W / 2) + (xx >> 1);
#pragma unroll
        for (int rr = 0; rr < 4; rr++) {
          float v = acc[mi][nf][rr] + bv[rr];
          if (ACC)
            v += bf2f(accsrc[((size_t)(bb2 * CDIM + oc0 + rr) * 4 + ph) * (HW / 4) + q]);
          o[((size_t)(bb2 * CDIM + oc0 + rr)) * HW + pin] = lrelu(v);
        }
      } else {
        unsigned short* o = (unsigned short*)outp;
        ushort4 pk;
        pk.x = f2bf(lrelu(acc[mi][nf][0] + bv[0]));
        pk.y = f2bf(lrelu(acc[mi][nf][1] + bv[1]));
        pk.z = f2bf(lrelu(acc[mi][nf][2] + bv[2]));
        pk.w = f2bf(lrelu(acc[mi][nf][3] + bv[3]));
        *(ushort4*)&o[(size_t)p * CDIM + oc0] = pk;
      }
    }
  }
}

// ---------------- phase-collapsed upsample-conv: 4-tap GEMM on lf grid ----------------
// out-phase (a,bp): out_hf[2Y+a, 2X+bp] += sum_{ty,tx} lf[clamp(Y-1+a+ty), clamp(X-1+bp+tx)] . Wph
// block = 64 oc x 256 lf-px (4 rows x 64 cols), one phase. Writes compact
// bf16 phase buffer [b][oc][phase][64][64], consumed by h2h's ACC epilogue.
__global__ __launch_bounds__(256, 3) void k_conv_up(
    const unsigned short* __restrict__ lf, const unsigned short* __restrict__ wph,
    unsigned short* __restrict__ phb) {
  constexpr int NIT = 5;                      // 5 rows x 64 cols staged
  __shared__ __align__(16) unsigned short tin[320 * 64 / 2];      // 320 slots x 32ic x 2B
  __shared__ __align__(16) unsigned short wlds[4 * 256 * 8];      // 4 taps

  const int t = threadIdx.x;
  const int l = t & 63, wv = t >> 6;
  const int l15 = l & 15, l4 = l >> 4;

  const int hwid = blockIdx.x;
  const int wk = (hwid & 7) * 128 + (hwid >> 3);   // nwg = 1024
  const int mb = wk & 3;
  const int phase = (wk >> 2) & 3;
  const int tile = (wk >> 4) & 15;
  const int b = wk >> 8;
  const int a = phase >> 1, bp = phase & 1;
  const int Y0 = tile * 4;

  f32x4 acc[4][4];
#pragma unroll
  for (int mi = 0; mi < 4; mi++)
#pragma unroll
    for (int nf = 0; nf < 4; nf++) acc[mi][nf] = (f32x4){0.f, 0.f, 0.f, 0.f};

  const unsigned short* inptr[NIT];
#pragma unroll
  for (int it = 0; it < NIT; ++it) {
    int s = it * 64 + (t >> 2);
    int row = s >> 6, col = s & 63;
    int ly = Y0 - 1 + a + row;
    ly = ly < 0 ? 0 : (ly > 63 ? 63 : ly);
    int gsrc = (t & 3) ^ (col & 3);
    inptr[it] = lf + (((size_t)(b * 64 + ly) * 64 + col) * CDIM + gsrc * 8);
  }
  const unsigned short* wsrc = wph + ((size_t)(mb * 4 + wv) * 64 + l) * 8;

  for (int icc = 0; icc < 8; ++icc) {
    __syncthreads();
#pragma unroll
    for (int it = 0; it < NIT; ++it)
      gload_lds16(inptr[it] + icc * 32, &tin[(size_t)(it * 256 + t) * 8]);
#pragma unroll
    for (int tap = 0; tap < 4; ++tap)
      gload_lds16(wsrc + ((size_t)(phase * 4 + tap) * 8 + (size_t)icc) * 8192,
                  &wlds[(size_t)(tap * 256 + t) * 8]);
    __syncthreads();

    __builtin_amdgcn_s_setprio(1);
#pragma unroll
    for (int tap = 0; tap < 4; ++tap) {
      const int ty = tap >> 1, tx = tap & 1;
      bf16x8 af[4];
#pragma unroll
      for (int mi = 0; mi < 4; mi++)
        af[mi] = *(const bf16x8*)&wlds[(size_t)((tap * 4 + mi) * 64 + l) * 8];
#pragma unroll
      for (int nf = 0; nf < 4; nf++) {
        int pl = wv * 64 + nf * 16 + l15;
        int py = pl >> 6;
        int col = pl & 63;
        int tcol = col - 1 + bp + tx;
        tcol = tcol < 0 ? 0 : (tcol > 63 ? 63 : tcol);
        int idx16 = ((py + ty) * 64 + tcol) * 4 + (l4 ^ (tcol & 3));
        bf16x8 bfv = *(const bf16x8*)&tin[(size_t)idx16 * 8];
#pragma unroll
        for (int mi = 0; mi < 4; mi++)
          acc[mi][nf] = __builtin_amdgcn_mfma_f32_16x16x32_bf16(af[mi], bfv, acc[mi][nf], 0, 0, 0);
      }
    }
    __builtin_amdgcn_s_setprio(0);
  }

  // coalesced write into bf16 phase buffer
#pragma unroll
  for (int mi = 0; mi < 4; mi++) {
    int oc0 = mb * 64 + mi * 16 + l4 * 4;
#pragma unroll
    for (int nf = 0; nf < 4; nf++) {
      int pl = wv * 64 + nf * 16 + l15;
      int py = pl >> 6, col = pl & 63;
      size_t base = ((size_t)(b * CDIM + oc0) * 4 + phase) * 4096 + (Y0 + py) * 64 + col;
#pragma unroll
      for (int rr = 0; rr < 4; rr++)
        phb[base + (size_t)rr * 4 * 4096] = f2bf(acc[mi][nf][rr]);
    }
  }
}

// ---------------- host ----------------
extern "C" void kernel_launch(void* const* d_in, const int* in_sizes, int n_in,
                              void* d_out, int out_size, void* d_ws, size_t ws_size,
                              hipStream_t stream) {
  (void)in_sizes; (void)n_in; (void)out_size;
  const float* c_hf = (const float*)d_in[0];
  const float* c_lf = (const float*)d_in[1];
  const float* s_hf = (const float*)d_in[2];
  const float* s_lf = (const float*)d_in[3];
  const float* h_sw = (const float*)d_in[4];
  const float* h_sb = (const float*)d_in[5];
  const float* h_pw = (const float*)d_in[6];
  const float* h_pb = (const float*)d_in[7];
  const float* h_bw = (const float*)d_in[8];
  const float* h_bb = (const float*)d_in[9];
  const float* l_sw = (const float*)d_in[10];
  const float* l_sb = (const float*)d_in[11];
  const float* l_pw = (const float*)d_in[12];
  const float* l_pb = (const float*)d_in[13];
  const float* l_bw = (const float*)d_in[14];
  const float* l_bb = (const float*)d_in[15];
  const float* ada_h_w = (const float*)d_in[16];
  const float* ada_h_b = (const float*)d_in[17];
  const float* ada_l_w = (const float*)d_in[18];
  const float* ada_l_b = (const float*)d_in[19];
  const float* h2h = (const float*)d_in[20];
  const float* l2h = (const float*)d_in[21];
  const float* h2l = (const float*)d_in[22];
  const float* l2l = (const float*)d_in[23];

  const int B = 4, H = 128, W = 128;

  float* base;
  size_t need = (size_t)TOTAL_F * sizeof(float);
  if (ws_size >= need) {
    base = (float*)d_ws;
  } else {
    void* p = nullptr;
    hipGetSymbolAddress(&p, HIP_SYMBOL(g_scratch));
    base = (float*)p;
  }

  float* ws_hf = base + OFF_WS_HF;
  float* ws_lf = base + OFF_WS_LF;
  float* wp_hf = base + OFF_WP_HF;
  float* bs_hf = base + OFF_BS_HF;
  float* wp_lf = base + OFF_WP_LF;
  float* bs_lf = base + OFF_BS_LF;
  float* mean_hf = base + OFF_MEAN_HF;
  float* rstd_hf = base + OFF_RSTD_HF;
  float* mean_lf = base + OFF_MEAN_LF;
  float* rstd_lf = base + OFF_RSTD_LF;
  unsigned short* u16 = (unsigned short*)(base + OFF_U16);
  unsigned short* yh = u16 + U_YH;
  unsigned short* yl = u16 + U_YL;
  unsigned short* hfA = u16 + U_HFA;
  unsigned short* lfA = u16 + U_LFA;
  unsigned short* hfP = u16 + U_HFP;
  unsigned short* pk      = u16 + U_PK;
  unsigned short* pk_adah = pk + 0 * PK_SZ;
  unsigned short* pk_h2h  = pk + 1 * PK_SZ;
  unsigned short* pk_adal = pk + 3 * PK_SZ;
  unsigned short* pk_l2l  = pk + 4 * PK_SZ;
  unsigned short* pk_h2l  = pk + 5 * PK_SZ;
  unsigned short* pk_ph   = u16 + U_PKPH;
  unsigned short* phb     = u16 + U_PHB;

  float* out_hf = (float*)d_out;
  float* out_lf = (float*)d_out + 16777216;

  // weight packing (all in one launch)
  k_packall<<<dim3(4096, 6), dim3(256), 0, stream>>>(ada_h_w, h2h, ada_l_w, l2l, h2l, l2h,
                                                     pk, pk_ph);

  // kernel_predict (hf & lf fused per stage)
  k_ws<<<dim3(B * CDIM, 2), dim3(256), 0, stream>>>(s_hf, h_sw, h_sb, ws_hf,
                                                    s_lf, l_sw, l_sb, ws_lf);
  k_point<<<dim3(B, 2), dim3(256), 0, stream>>>(s_hf, h_pw, h_pb, h_bw, h_bb, wp_hf, bs_hf,
                                                s_lf, l_pw, l_pb, l_bw, l_bb, wp_lf, bs_lf);

  // instance norm stats (both freqs)
  k_istats<<<dim3(2048), dim3(256), 0, stream>>>(c_hf, mean_hf, rstd_hf,
                                                 c_lf, mean_lf, rstd_lf);

  // fused IN + depthwise + pointwise -> NHWC bf16
  k_dwt<7><<<dim3(8, 128, 4), dim3(256), 0, stream>>>(c_hf, ws_hf, mean_hf, rstd_hf, wp_hf, bs_hf, yh);
  k_dwt<6><<<dim3(4, 64, 4), dim3(256), 0, stream>>>(c_lf, ws_lf, mean_lf, rstd_lf, wp_lf, bs_lf, yl);

  // ada convs (MFMA), bf16 NHWC out, lrelu
  k_conv_mfma<7, false, false, false, false><<<dim3(1024), dim3(256), 0, stream>>>(
      yh, nullptr, pk_adah, nullptr, ada_h_b, nullptr, hfA);
  k_conv_mfma<6, false, false, false, false><<<dim3(256), dim3(256), 0, stream>>>(
      yl, nullptr, pk_adal, nullptr, ada_l_b, nullptr, lfA);

  // phase-collapsed conv(up(lf), l2h) -> bf16 phase buffer
  k_conv_up<<<dim3(1024), dim3(256), 0, stream>>>(lfA, pk_ph, phb);

  // avgpool hf (vectorized)
  k_pool_nhwc<<<dim3(2048), dim3(256), 0, stream>>>(hfA, hfP);

  // hf_out = lrelu(conv(hf,h2h) + phase buffer)
  k_conv_mfma<7, false, false, true, true><<<dim3(1024), dim3(256), 0, stream>>>(
      hfA, nullptr, pk_h2h, nullptr, nullptr, phb, out_hf);

  // lf_out = lrelu(conv(lf,l2l) + conv(avgpool2(hf),h2l))
  k_conv_mfma<6, true, false, true, false><<<dim3(256), dim3(256), 0, stream>>>(
      lfA, hfP, pk_l2l, pk_h2l, nullptr, nullptr, out_lf);
}

// Round 11
// 383.622 us; speedup vs baseline: 1.4837x; 1.1993x over previous
//
#include <hip/hip_runtime.h>
#include <hip/hip_bf16.h>

#define CDIM 256
#define EPS 1e-5f
#define SLOPE 0.01f

using f32x4  = __attribute__((ext_vector_type(4))) float;
typedef __bf16 bf16x8 __attribute__((ext_vector_type(8)));
typedef unsigned short u16x8 __attribute__((ext_vector_type(8)));

// ---------------- workspace layout ----------------
enum : size_t {
  OFF_WS_HF   = 0,
  OFF_WS_LF   = 9216,
  OFF_WP_HF   = 20480,
  OFF_BS_HF   = 21504,
  OFF_WP_LF   = 22528,
  OFF_BS_LF   = 23552,
  OFF_MEAN_HF = 24576,
  OFF_RSTD_HF = 25600,
  OFF_MEAN_LF = 26624,
  OFF_RSTD_LF = 27648,
  OFF_U16     = 32768,          // start of ushort region (float units)
};
// ushort offsets relative to u16 base
enum : size_t {
  U_YH  = 0,          // [4][128][128][256] bf16
  U_YL  = 16777216,   // [4][64][64][256]
  U_HFA = 20971520,   // [4][128][128][256]
  U_LFA = 37748736,   // [4][64][64][256]
  U_HFP = 41943040,   // [4][64][64][256]
  U_PK  = 46137344,   // 6 packed weight slots, each 589824 (slot2 unused)
  PK_SZ = 589824,
  U_PKPH = U_PK + 6 * PK_SZ,    // phase-packed l2h: 4ph x 4tap x 8icc x 16mf x 64 x 8
  PH_SZ  = 1048576,
  U_PHB  = U_PKPH + PH_SZ,      // phase buffer [4][256][4][64][64] bf16
  U_END  = U_PHB + 16777216,
};
enum : size_t { TOTAL_F = OFF_U16 + (U_END + 1) / 2 };

__device__ float g_scratch[TOTAL_F];

__device__ __forceinline__ int refl(int q, int n) {
  return q < 0 ? -q : (q >= n ? 2 * n - 2 - q : q);
}
__device__ __forceinline__ float lrelu(float v) { return v >= 0.f ? v : SLOPE * v; }
__device__ __forceinline__ unsigned short f2bf(float f) {
  unsigned int u = __float_as_uint(f);
  u += 0x7fffu + ((u >> 16) & 1u);
  return (unsigned short)(u >> 16);
}
__device__ __forceinline__ float bf2f(unsigned short h) {
  return __uint_as_float(((unsigned int)h) << 16);
}
__device__ __forceinline__ void gload_lds16(const void* g, void* l) {
  __builtin_amdgcn_global_load_lds(
      (const __attribute__((address_space(1))) unsigned int*)g,
      (__attribute__((address_space(3))) unsigned int*)l, 16, 0, 0);
}

// ---------------- kernel_predict: spatial weights (hf & lf in one launch) ----------------
__global__ __launch_bounds__(256) void k_ws(const float* __restrict__ s_hf,
                                            const float* __restrict__ sw_hf,
                                            const float* __restrict__ sb_hf,
                                            float* __restrict__ ws_hf,
                                            const float* __restrict__ s_lf,
                                            const float* __restrict__ sw_lf,
                                            const float* __restrict__ sb_lf,
                                            float* __restrict__ ws_lf) {
  const bool lf = blockIdx.y != 0;
  const float* s  = lf ? s_lf : s_hf;
  const float* sw = lf ? sw_lf : sw_hf;
  const float* sb = lf ? sb_lf : sb_hf;
  float* ws_out   = lf ? ws_lf : ws_hf;
  int bo = blockIdx.x;
  int o = bo & (CDIM - 1);
  int c = threadIdx.x;
  int b = bo >> 8;
  float sv[9], wv[9];
  const float* sp = s + (size_t)(b * CDIM + c) * 9;
  const float* wp = sw + (size_t)(o * CDIM + c) * 9;
#pragma unroll
  for (int i = 0; i < 9; i++) { sv[i] = sp[i]; wv[i] = wp[i]; }
  float out9[9];
#pragma unroll
  for (int i = 0; i < 3; i++)
#pragma unroll
    for (int j = 0; j < 3; j++) {
      float a = 0.f;
#pragma unroll
      for (int dy = 0; dy < 3; dy++) {
        int u = i + dy - 1; u = (u < 0) ? 1 : (u > 2 ? 1 : u);
#pragma unroll
        for (int dx = 0; dx < 3; dx++) {
          int v = j + dx - 1; v = (v < 0) ? 1 : (v > 2 ? 1 : v);
          a += sv[u * 3 + v] * wv[dy * 3 + dx];
        }
      }
      out9[i * 3 + j] = a;
    }
  __shared__ float red[256 * 9];
#pragma unroll
  for (int i = 0; i < 9; i++) red[c * 9 + i] = out9[i];
  __syncthreads();
  for (int st = 128; st > 0; st >>= 1) {
    if (c < st)
#pragma unroll
      for (int i = 0; i < 9; i++) red[c * 9 + i] += red[(c + st) * 9 + i];
    __syncthreads();
  }
  if (c < 9) ws_out[(size_t)bo * 9 + c] = red[c] + sb[o];
}

// ---------------- pooled + w_point / bias (hf & lf in one launch, float4) ----------------
__global__ __launch_bounds__(256) void k_point(const float* __restrict__ s_hf,
                                               const float* __restrict__ pw_hf,
                                               const float* __restrict__ pb_hf,
                                               const float* __restrict__ bw_hf,
                                               const float* __restrict__ bb_hf,
                                               float* __restrict__ wp_hf,
                                               float* __restrict__ bs_hf,
                                               const float* __restrict__ s_lf,
                                               const float* __restrict__ pw_lf,
                                               const float* __restrict__ pb_lf,
                                               const float* __restrict__ bw_lf,
                                               const float* __restrict__ bb_lf,
                                               float* __restrict__ wp_lf,
                                               float* __restrict__ bs_lf) {
  const bool lf = blockIdx.y != 0;
  const float* s  = lf ? s_lf : s_hf;
  const float* pw = lf ? pw_lf : pw_hf;
  const float* pb = lf ? pb_lf : pb_hf;
  const float* bw = lf ? bw_lf : bw_hf;
  const float* bb = lf ? bb_lf : bb_hf;
  float* wp_out = lf ? wp_lf : wp_hf;
  float* bs_out = lf ? bs_lf : bs_hf;
  int b = blockIdx.x, o = threadIdx.x;
  __shared__ float pl[CDIM];
  const float* sp = s + (size_t)(b * CDIM + o) * 9;
  float a9 = 0.f;
#pragma unroll
  for (int j = 0; j < 9; j++) a9 += sp[j];
  pl[o] = a9 * (1.f / 9.f);
  __syncthreads();
  float a = pb[o], d = bb[o];
  const float4* pw4 = (const float4*)(pw + (size_t)o * CDIM);
  const float4* bw4 = (const float4*)(bw + (size_t)o * CDIM);
  const float4* pl4 = (const float4*)pl;
  for (int c4 = 0; c4 < CDIM / 4; c4++) {
    float4 p = pl4[c4];
    float4 w1 = pw4[c4], w2 = bw4[c4];
    a += p.x * w1.x + p.y * w1.y + p.z * w1.z + p.w * w1.w;
    d += p.x * w2.x + p.y * w2.y + p.z * w2.z + p.w * w2.w;
  }
  wp_out[b * CDIM + o] = a;
  bs_out[b * CDIM + o] = d;
}

// ---------------- instance norm stats (hf & lf in one launch) ----------------
__global__ __launch_bounds__(256) void k_istats(const float* __restrict__ xh,
                                                float* __restrict__ mh, float* __restrict__ rh,
                                                const float* __restrict__ xl,
                                                float* __restrict__ ml, float* __restrict__ rl) {
  const bool lf = blockIdx.x >= 1024;
  int plane = lf ? blockIdx.x - 1024 : blockIdx.x;
  const float* x = lf ? xl : xh;
  float* mean = lf ? ml : mh;
  float* rstd = lf ? rl : rh;
  const int HW = lf ? 4096 : 16384;
  const float4* p = (const float4*)(x + (size_t)plane * HW);
  int n4 = HW >> 2;
  float s = 0.f, q = 0.f;
  for (int i = threadIdx.x; i < n4; i += 256) {
    float4 v = p[i];
    s += v.x + v.y + v.z + v.w;
    q += v.x * v.x + v.y * v.y + v.z * v.z + v.w * v.w;
  }
  __shared__ float rs[256], rq[256];
  rs[threadIdx.x] = s; rq[threadIdx.x] = q;
  __syncthreads();
  for (int st = 128; st > 0; st >>= 1) {
    if (threadIdx.x < st) {
      rs[threadIdx.x] += rs[threadIdx.x + st];
      rq[threadIdx.x] += rq[threadIdx.x + st];
    }
    __syncthreads();
  }
  if (threadIdx.x == 0) {
    float m = rs[0] / HW;
    float v = rq[0] / HW - m * m;
    mean[plane] = m;
    rstd[plane] = rsqrtf(v + EPS);
  }
}

// ---------------- all weight packing in one launch ----------------
__global__ void k_packall(const float* __restrict__ w_adah, const float* __restrict__ w_h2h,
                          const float* __restrict__ w_adal, const float* __restrict__ w_l2l,
                          const float* __restrict__ w_h2l, const float* __restrict__ w_l2h,
                          unsigned short* __restrict__ pk, unsigned short* __restrict__ pkph) {
  int seg = blockIdx.y;
  int i = blockIdx.x * 256 + threadIdx.x;
  if (seg < 5) {
    if (i >= 589824) return;
    const float* srcs[5] = {w_adah, w_h2h, w_adal, w_l2l, w_h2l};
    const int slot[5] = {0, 1, 3, 4, 5};
    const float* w = srcs[seg];
    int j = i & 7, l = (i >> 3) & 63, mf = (i >> 9) & 15, icc = (i >> 13) & 7, tap = i >> 16;
    int oc = mf * 16 + (l & 15);
    int ic = icc * 32 + (l >> 4) * 8 + j;
    pk[(size_t)slot[seg] * PK_SZ + i] = f2bf(w[((size_t)oc * 256 + ic) * 9 + tap]);
  } else {
    // phase pack: i < 1048576
    int j = i & 7, l = (i >> 3) & 63, mf = (i >> 9) & 15, icc = (i >> 13) & 7, tapph = i >> 16;
    int tap = tapph & 3, phase = tapph >> 2;
    int tx = tap & 1, ty = tap >> 1;
    int a = phase >> 1, bp = phase & 1;
    int oc = mf * 16 + (l & 15);
    int ic = icc * 32 + (l >> 4) * 8 + j;
    int ys = (a == 0) ? (ty == 0 ? 0 : 1) : (ty == 0 ? 0 : 2);
    int yc = (a == 0) ? (ty == 0 ? 1 : 2) : (ty == 0 ? 2 : 1);
    int xs = (bp == 0) ? (tx == 0 ? 0 : 1) : (tx == 0 ? 0 : 2);
    int xc = (bp == 0) ? (tx == 0 ? 1 : 2) : (tx == 0 ? 2 : 1);
    const float* wb = w_l2h + ((size_t)oc * 256 + ic) * 9;
    float acc = 0.f;
    for (int dy = ys; dy < ys + yc; dy++)
      for (int dx = xs; dx < xs + xc; dx++) acc += wb[dy * 3 + dx];
    pkph[i] = f2bf(acc);
  }
}

// ---------------- fused IN + dynamic depthwise + pointwise -> NHWC bf16 ----------------
// vectorized: each thread processes 4 consecutive pixels per channel-pass via
// float4 row loads (+2 edge scalars); taps from in-register neighbors.
template <int LW>
__global__ __launch_bounds__(256) void k_dwt(const float* __restrict__ x,
                                             const float* __restrict__ ws,
                                             const float* __restrict__ mean,
                                             const float* __restrict__ rstd,
                                             const float* __restrict__ wp,
                                             const float* __restrict__ bs,
                                             unsigned short* __restrict__ out) {
  constexpr int W = 1 << LW, H = W, HW = W * W;
  int t = threadIdx.x;
  int xt = (LW > 6) ? (blockIdx.x & ((W >> 6) - 1)) : 0;
  int icb = (LW > 6) ? (blockIdx.x >> (LW - 6)) : blockIdx.x;
  int y = blockIdx.y, b = blockIdx.z;
  __shared__ unsigned short tr[64][66];
  const int xg = t & 15;                 // 16 groups of 4 px -> 64 px
  const int chq = t >> 4;                // 0..15
  const int x0 = xt * 64 + xg * 4;
  const int sy0 = refl(y - 1, H), sy2 = refl(y + 1, H);
  const int xm = refl(x0 - 1, W);        // left edge neighbor
  const int xq = refl(x0 + 4, W);        // right edge neighbor
#pragma unroll
  for (int rr = 0; rr < 4; ++rr) {
    int icl = rr * 16 + chq;
    int plane = b * CDIM + icb * 64 + icl;
    const float* xpb = x + (size_t)plane * HW;
    float m = mean[plane], r = rstd[plane], sc = wp[plane], bi = bs[plane];
    const float* w9p = ws + (size_t)plane * 9;
    float w9[9];
#pragma unroll
    for (int i = 0; i < 9; i++) w9[i] = w9p[i];
    float sumw = w9[0] + w9[1] + w9[2] + w9[3] + w9[4] + w9[5] + w9[6] + w9[7] + w9[8];
    const float* r0 = xpb + sy0 * W;
    const float* r1 = xpb + y * W;
    const float* r2 = xpb + sy2 * W;
    float4 v0 = *(const float4*)(r0 + x0);
    float4 v1 = *(const float4*)(r1 + x0);
    float4 v2 = *(const float4*)(r2 + x0);
    float e0[6] = {r0[xm], v0.x, v0.y, v0.z, v0.w, r0[xq]};
    float e1[6] = {r1[xm], v1.x, v1.y, v1.z, v1.w, r1[xq]};
    float e2[6] = {r2[xm], v2.x, v2.y, v2.z, v2.w, r2[xq]};
    float mterm = m * sumw;
#pragma unroll
    for (int j = 0; j < 4; ++j) {
      float a = w9[0] * e0[j] + w9[1] * e0[j + 1] + w9[2] * e0[j + 2] +
                w9[3] * e1[j] + w9[4] * e1[j + 1] + w9[5] * e1[j + 2] +
                w9[6] * e2[j] + w9[7] * e2[j + 1] + w9[8] * e2[j + 2];
      a -= mterm;
      tr[icl][xg * 4 + j] = f2bf(a * r * sc + bi);
    }
  }
  __syncthreads();
  // vectorized NHWC store: 64 px x 64 ch, u16x8 per store
#pragma unroll
  for (int it2 = 0; it2 < 2; ++it2) {
    int s2 = it2 * 256 + t;          // 0..511
    int xl2 = s2 >> 3;               // 0..63
    int cg = s2 & 7;                 // 0..7
    u16x8 v;
#pragma unroll
    for (int j = 0; j < 8; j++) v[j] = tr[cg * 8 + j][xl2];
    *(u16x8*)&out[((size_t)((b * H + y) * W + xt * 64 + xl2)) * CDIM + icb * 64 + cg * 8] = v;
  }
}

// ---------------- 2x2 avg pool on NHWC bf16 (vectorized: 8 ch / thread) ----------------
__global__ __launch_bounds__(256) void k_pool_nhwc(const unsigned short* __restrict__ in,
                                                   unsigned short* __restrict__ out) {
  int i = blockIdx.x * 256 + threadIdx.x;   // < 4*64*64*32
  int cg = i & 31;
  int p = i >> 5;                            // (b*64+Y)*64+X
  int X = p & 63, Y = (p >> 6) & 63, b = p >> 12;
  const unsigned short* s =
      in + ((size_t)(b * 128 + 2 * Y) * 128 + 2 * X) * CDIM + cg * 8;
  u16x8 v0 = *(const u16x8*)(s);
  u16x8 v1 = *(const u16x8*)(s + CDIM);
  u16x8 v2 = *(const u16x8*)(s + 128 * CDIM);
  u16x8 v3 = *(const u16x8*)(s + 128 * CDIM + CDIM);
  u16x8 r;
#pragma unroll
  for (int j = 0; j < 8; j++)
    r[j] = f2bf(0.25f * (bf2f(v0[j]) + bf2f(v1[j]) + bf2f(v2[j]) + bf2f(v3[j])));
  *(u16x8*)(out + (size_t)p * CDIM + cg * 8) = r;
}

// ---------------- MFMA implicit-GEMM 3x3 reflect conv (R5 structure + ACC) ----------------
template <int LW, bool DUAL, bool UPSB, bool NCHWOUT, bool ACC>
__global__ __launch_bounds__(256, 2) void k_conv_mfma(
    const unsigned short* __restrict__ srcA, const unsigned short* __restrict__ srcB,
    const unsigned short* __restrict__ wpkA, const unsigned short* __restrict__ wpkB,
    const float* __restrict__ bias, const unsigned short* __restrict__ accsrc,
    void* __restrict__ outp) {
  constexpr int W = 1 << LW, H = W, HW = W * W;
  constexpr int ROWS = 256 >> LW;       // pixel rows per block
  constexpr int R = ROWS + 2, Cw = W + 2;
  constexpr int RC = R * Cw;
  constexpr int RCPAD = (RC + 63) & ~63;
  constexpr int NIT = RCPAD / 64;
  __shared__ __align__(16) unsigned short tin[RCPAD * 32];        // input tile, 32 ic
  __shared__ __align__(16) unsigned short wlds[9 * 4 * 64 * 8];   // 9 taps x 4 mi frags

  const int t = threadIdx.x;
  const int l = t & 63, wv = t >> 6;
  const int l15 = l & 15, l4 = l >> 4;

  // XCD-chunked bijective swizzle (nwg divisible by 8)
  const int hwid = blockIdx.x;
  const int nwg = gridDim.x;
  const int wk = (hwid & 7) * (nwg >> 3) + (hwid >> 3);
  const int mb = wk & 3;
  const int pixbase = (wk >> 2) * 256;
  const int b = pixbase >> (2 * LW);
  const int y0 = (pixbase >> LW) & (H - 1);

  f32x4 acc[4][4];
#pragma unroll
  for (int mi = 0; mi < 4; mi++)
#pragma unroll
    for (int nf = 0; nf < 4; nf++) acc[mi][nf] = (f32x4){0.f, 0.f, 0.f, 0.f};

  const int nsrc = DUAL ? 2 : 1;
  for (int src = 0; src < nsrc; ++src) {
    const unsigned short* ysrc = src ? srcB : srcA;
    const unsigned short* wpk = src ? wpkB : wpkA;
    const bool ups = UPSB && (src == 1);

    // hoist staging addresses out of the K loop
    const unsigned short* inptr[NIT];
#pragma unroll
    for (int it = 0; it < NIT; ++it) {
      int rc = it * 64 + (t >> 2);
      int rcc = rc < RC - 1 ? rc : RC - 1;
      int r = rcc / Cw, tc = rcc - r * Cw;
      int gy = refl(y0 - 1 + r, H);
      int gx = refl(tc - 1, W);
      int sy, sx, sw;
      if (ups) { sy = gy >> 1; sx = gx >> 1; sw = W >> 1; }
      else     { sy = gy;      sx = gx;      sw = W; }
      int gsrc = (t & 3) ^ (tc & 3);   // ic-slot XOR swizzle (source side)
      inptr[it] = ysrc + (((size_t)(b * sw + sy) * sw + sx) * CDIM + gsrc * 8);
    }
    const unsigned short* wsrc = wpk + ((size_t)(mb * 4 + wv) * 64 + l) * 8;

    for (int icc = 0; icc < 8; ++icc) {
      __syncthreads();
#pragma unroll
      for (int it = 0; it < NIT; ++it)
        gload_lds16(inptr[it] + icc * 32, &tin[(size_t)(it * 256 + t) * 8]);
#pragma unroll
      for (int tap = 0; tap < 9; ++tap)
        gload_lds16(wsrc + ((size_t)tap * 8 + (size_t)icc) * 8192,
                    &wlds[(size_t)(tap * 256 + t) * 8]);
      __syncthreads();

      __builtin_amdgcn_s_setprio(1);
#pragma unroll
      for (int tap = 0; tap < 9; ++tap) {
        const int dy = tap / 3, dx = tap - 3 * (tap / 3);
        bf16x8 af[4];
#pragma unroll
        for (int mi = 0; mi < 4; mi++)
          af[mi] = *(const bf16x8*)&wlds[(size_t)((tap * 4 + mi) * 64 + l) * 8];
#pragma unroll
        for (int nf = 0; nf < 4; nf++) {
          int pl = wv * 64 + nf * 16 + l15;
          int py = pl >> LW;
          int c = pl & (W - 1);
          int tcol = c + dx;
          int idx16 = ((py + dy) * Cw + tcol) * 4 + (l4 ^ (tcol & 3));
          bf16x8 bfv = *(const bf16x8*)&tin[(size_t)idx16 * 8];
#pragma unroll
          for (int mi = 0; mi < 4; mi++)
            acc[mi][nf] = __builtin_amdgcn_mfma_f32_16x16x32_bf16(af[mi], bfv, acc[mi][nf], 0, 0, 0);
        }
      }
      __builtin_amdgcn_s_setprio(0);
    }
  }

  // epilogue
#pragma unroll
  for (int mi = 0; mi < 4; mi++) {
    int oc0 = mb * 64 + mi * 16 + l4 * 4;
    float bv[4];
#pragma unroll
    for (int rr = 0; rr < 4; rr++) bv[rr] = bias ? bias[oc0 + rr] : 0.f;
#pragma unroll
    for (int nf = 0; nf < 4; nf++) {
      int p = pixbase + wv * 64 + nf * 16 + l15;
      if (NCHWOUT) {
        float* o = (float*)outp;
        int pin = p & (HW - 1);
        int bb2 = p >> (2 * LW);
        int yy = pin >> LW, xx = pin & (W - 1);
        int ph = ((yy & 1) << 1) | (xx & 1);
        int q = (yy >> 1) * (W / 2) + (xx >> 1);
#pragma unroll
        for (int rr = 0; rr < 4; rr++) {
          float v = acc[mi][nf][rr] + bv[rr];
          if (ACC)
            v += bf2f(accsrc[((size_t)(bb2 * CDIM + oc0 + rr) * 4 + ph) * (HW / 4) + q]);
          o[((size_t)(bb2 * CDIM + oc0 + rr)) * HW + pin] = lrelu(v);
        }
      } else {
        unsigned short* o = (unsigned short*)outp;
        ushort4 pk;
        pk.x = f2bf(lrelu(acc[mi][nf][0] + bv[0]));
        pk.y = f2bf(lrelu(acc[mi][nf][1] + bv[1]));
        pk.z = f2bf(lrelu(acc[mi][nf][2] + bv[2]));
        pk.w = f2bf(lrelu(acc[mi][nf][3] + bv[3]));
        *(ushort4*)&o[(size_t)p * CDIM + oc0] = pk;
      }
    }
  }
}

// ---------------- phase-collapsed upsample-conv: 4-tap GEMM on lf grid ----------------
__global__ __launch_bounds__(256, 3) void k_conv_up(
    const unsigned short* __restrict__ lf, const unsigned short* __restrict__ wph,
    unsigned short* __restrict__ phb) {
  constexpr int NIT = 5;                      // 5 rows x 64 cols staged
  __shared__ __align__(16) unsigned short tin[320 * 64 / 2];      // 320 slots x 32ic x 2B
  __shared__ __align__(16) unsigned short wlds[4 * 256 * 8];      // 4 taps

  const int t = threadIdx.x;
  const int l = t & 63, wv = t >> 6;
  const int l15 = l & 15, l4 = l >> 4;

  const int hwid = blockIdx.x;
  const int wk = (hwid & 7) * 128 + (hwid >> 3);   // nwg = 1024
  const int mb = wk & 3;
  const int phase = (wk >> 2) & 3;
  const int tile = (wk >> 4) & 15;
  const int b = wk >> 8;
  const int a = phase >> 1, bp = phase & 1;
  const int Y0 = tile * 4;

  f32x4 acc[4][4];
#pragma unroll
  for (int mi = 0; mi < 4; mi++)
#pragma unroll
    for (int nf = 0; nf < 4; nf++) acc[mi][nf] = (f32x4){0.f, 0.f, 0.f, 0.f};

  const unsigned short* inptr[NIT];
#pragma unroll
  for (int it = 0; it < NIT; ++it) {
    int s = it * 64 + (t >> 2);
    int row = s >> 6, col = s & 63;
    int ly = Y0 - 1 + a + row;
    ly = ly < 0 ? 0 : (ly > 63 ? 63 : ly);
    int gsrc = (t & 3) ^ (col & 3);
    inptr[it] = lf + (((size_t)(b * 64 + ly) * 64 + col) * CDIM + gsrc * 8);
  }
  const unsigned short* wsrc = wph + ((size_t)(mb * 4 + wv) * 64 + l) * 8;

  for (int icc = 0; icc < 8; ++icc) {
    __syncthreads();
#pragma unroll
    for (int it = 0; it < NIT; ++it)
      gload_lds16(inptr[it] + icc * 32, &tin[(size_t)(it * 256 + t) * 8]);
#pragma unroll
    for (int tap = 0; tap < 4; ++tap)
      gload_lds16(wsrc + ((size_t)(phase * 4 + tap) * 8 + (size_t)icc) * 8192,
                  &wlds[(size_t)(tap * 256 + t) * 8]);
    __syncthreads();

    __builtin_amdgcn_s_setprio(1);
#pragma unroll
    for (int tap = 0; tap < 4; ++tap) {
      const int ty = tap >> 1, tx = tap & 1;
      bf16x8 af[4];
#pragma unroll
      for (int mi = 0; mi < 4; mi++)
        af[mi] = *(const bf16x8*)&wlds[(size_t)((tap * 4 + mi) * 64 + l) * 8];
#pragma unroll
      for (int nf = 0; nf < 4; nf++) {
        int pl = wv * 64 + nf * 16 + l15;
        int py = pl >> 6;
        int col = pl & 63;
        int tcol = col - 1 + bp + tx;
        tcol = tcol < 0 ? 0 : (tcol > 63 ? 63 : tcol);
        int idx16 = ((py + ty) * 64 + tcol) * 4 + (l4 ^ (tcol & 3));
        bf16x8 bfv = *(const bf16x8*)&tin[(size_t)idx16 * 8];
#pragma unroll
        for (int mi = 0; mi < 4; mi++)
          acc[mi][nf] = __builtin_amdgcn_mfma_f32_16x16x32_bf16(af[mi], bfv, acc[mi][nf], 0, 0, 0);
      }
    }
    __builtin_amdgcn_s_setprio(0);
  }

  // coalesced write into bf16 phase buffer
#pragma unroll
  for (int mi = 0; mi < 4; mi++) {
    int oc0 = mb * 64 + mi * 16 + l4 * 4;
#pragma unroll
    for (int nf = 0; nf < 4; nf++) {
      int pl = wv * 64 + nf * 16 + l15;
      int py = pl >> 6, col = pl & 63;
      size_t base = ((size_t)(b * CDIM + oc0) * 4 + phase) * 4096 + (Y0 + py) * 64 + col;
#pragma unroll
      for (int rr = 0; rr < 4; rr++)
        phb[base + (size_t)rr * 4 * 4096] = f2bf(acc[mi][nf][rr]);
    }
  }
}

// ---------------- host ----------------
extern "C" void kernel_launch(void* const* d_in, const int* in_sizes, int n_in,
                              void* d_out, int out_size, void* d_ws, size_t ws_size,
                              hipStream_t stream) {
  (void)in_sizes; (void)n_in; (void)out_size;
  const float* c_hf = (const float*)d_in[0];
  const float* c_lf = (const float*)d_in[1];
  const float* s_hf = (const float*)d_in[2];
  const float* s_lf = (const float*)d_in[3];
  const float* h_sw = (const float*)d_in[4];
  const float* h_sb = (const float*)d_in[5];
  const float* h_pw = (const float*)d_in[6];
  const float* h_pb = (const float*)d_in[7];
  const float* h_bw = (const float*)d_in[8];
  const float* h_bb = (const float*)d_in[9];
  const float* l_sw = (const float*)d_in[10];
  const float* l_sb = (const float*)d_in[11];
  const float* l_pw = (const float*)d_in[12];
  const float* l_pb = (const float*)d_in[13];
  const float* l_bw = (const float*)d_in[14];
  const float* l_bb = (const float*)d_in[15];
  const float* ada_h_w = (const float*)d_in[16];
  const float* ada_h_b = (const float*)d_in[17];
  const float* ada_l_w = (const float*)d_in[18];
  const float* ada_l_b = (const float*)d_in[19];
  const float* h2h = (const float*)d_in[20];
  const float* l2h = (const float*)d_in[21];
  const float* h2l = (const float*)d_in[22];
  const float* l2l = (const float*)d_in[23];

  const int B = 4, H = 128, W = 128;

  float* base;
  size_t need = (size_t)TOTAL_F * sizeof(float);
  if (ws_size >= need) {
    base = (float*)d_ws;
  } else {
    void* p = nullptr;
    hipGetSymbolAddress(&p, HIP_SYMBOL(g_scratch));
    base = (float*)p;
  }

  float* ws_hf = base + OFF_WS_HF;
  float* ws_lf = base + OFF_WS_LF;
  float* wp_hf = base + OFF_WP_HF;
  float* bs_hf = base + OFF_BS_HF;
  float* wp_lf = base + OFF_WP_LF;
  float* bs_lf = base + OFF_BS_LF;
  float* mean_hf = base + OFF_MEAN_HF;
  float* rstd_hf = base + OFF_RSTD_HF;
  float* mean_lf = base + OFF_MEAN_LF;
  float* rstd_lf = base + OFF_RSTD_LF;
  unsigned short* u16 = (unsigned short*)(base + OFF_U16);
  unsigned short* yh = u16 + U_YH;
  unsigned short* yl = u16 + U_YL;
  unsigned short* hfA = u16 + U_HFA;
  unsigned short* lfA = u16 + U_LFA;
  unsigned short* hfP = u16 + U_HFP;
  unsigned short* pk      = u16 + U_PK;
  unsigned short* pk_adah = pk + 0 * PK_SZ;
  unsigned short* pk_h2h  = pk + 1 * PK_SZ;
  unsigned short* pk_adal = pk + 3 * PK_SZ;
  unsigned short* pk_l2l  = pk + 4 * PK_SZ;
  unsigned short* pk_h2l  = pk + 5 * PK_SZ;
  unsigned short* pk_ph   = u16 + U_PKPH;
  unsigned short* phb     = u16 + U_PHB;

  float* out_hf = (float*)d_out;
  float* out_lf = (float*)d_out + 16777216;

  // weight packing (all in one launch)
  k_packall<<<dim3(4096, 6), dim3(256), 0, stream>>>(ada_h_w, h2h, ada_l_w, l2l, h2l, l2h,
                                                     pk, pk_ph);

  // kernel_predict (hf & lf fused per stage)
  k_ws<<<dim3(B * CDIM, 2), dim3(256), 0, stream>>>(s_hf, h_sw, h_sb, ws_hf,
                                                    s_lf, l_sw, l_sb, ws_lf);
  k_point<<<dim3(B, 2), dim3(256), 0, stream>>>(s_hf, h_pw, h_pb, h_bw, h_bb, wp_hf, bs_hf,
                                                s_lf, l_pw, l_pb, l_bw, l_bb, wp_lf, bs_lf);

  // instance norm stats (both freqs)
  k_istats<<<dim3(2048), dim3(256), 0, stream>>>(c_hf, mean_hf, rstd_hf,
                                                 c_lf, mean_lf, rstd_lf);

  // fused IN + depthwise + pointwise -> NHWC bf16 (vectorized)
  k_dwt<7><<<dim3(8, 128, 4), dim3(256), 0, stream>>>(c_hf, ws_hf, mean_hf, rstd_hf, wp_hf, bs_hf, yh);
  k_dwt<6><<<dim3(4, 64, 4), dim3(256), 0, stream>>>(c_lf, ws_lf, mean_lf, rstd_lf, wp_lf, bs_lf, yl);

  // ada convs (MFMA), bf16 NHWC out, lrelu
  k_conv_mfma<7, false, false, false, false><<<dim3(1024), dim3(256), 0, stream>>>(
      yh, nullptr, pk_adah, nullptr, ada_h_b, nullptr, hfA);
  k_conv_mfma<6, false, false, false, false><<<dim3(256), dim3(256), 0, stream>>>(
      yl, nullptr, pk_adal, nullptr, ada_l_b, nullptr, lfA);

  // phase-collapsed conv(up(lf), l2h) -> bf16 phase buffer
  k_conv_up<<<dim3(1024), dim3(256), 0, stream>>>(lfA, pk_ph, phb);

  // avgpool hf (vectorized)
  k_pool_nhwc<<<dim3(2048), dim3(256), 0, stream>>>(hfA, hfP);

  // hf_out = lrelu(conv(hf,h2h) + phase buffer)
  k_conv_mfma<7, false, false, true, true><<<dim3(1024), dim3(256), 0, stream>>>(
      hfA, nullptr, pk_h2h, nullptr, nullptr, phb, out_hf);

  // lf_out = lrelu(conv(lf,l2l) + conv(avgpool2(hf),h2l))
  k_conv_mfma<6, true, false, true, false><<<dim3(256), dim3(256), 0, stream>>>(
      lfA, hfP, pk_l2l, pk_h2l, nullptr, nullptr, out_lf);
}